// Round 3
// baseline (629.199 us; speedup 1.0000x reference)
//
#include <hip/hip_runtime.h>

#define NB 2
#define NT 2048
#define ND 1024
#define NH 16
#define HD 64
#define WIN 512
#define NBH (NB*NH)      // 32
#define NCH (NT/64)      // 32 chunks of 64 along T

// ---------------------------------------------------------------- helpers
__device__ __forceinline__ void fma16(const float4 av, const float4 bv, float acc[4][4])
{
    float ar[4] = {av.x, av.y, av.z, av.w};
    float br[4] = {bv.x, bv.y, bv.z, bv.w};
#pragma unroll
    for (int r = 0; r < 4; ++r)
#pragma unroll
        for (int c = 0; c < 4; ++c)
            acc[r][c] = fmaf(ar[r], br[c], acc[r][c]);
}

// Transposed store of 16 consecutive d-values into dst[d][jj], with XOR
// swizzle col' = jj ^ (d&48) -> 2 accesses/bank (minimum) instead of 4.
__device__ __forceinline__ void storeT(float (*dst)[64], int d0, int jj,
                                       const float4* q)
{
#pragma unroll
    for (int h = 0; h < 4; ++h) {
        const float vals[4] = {q[h].x, q[h].y, q[h].z, q[h].w};
#pragma unroll
        for (int r = 0; r < 4; ++r) {
            const int d = d0 + (h << 2) + r;
            dst[d][(jj ^ (d & 48))] = vals[r];
        }
    }
}

// ---------------------------------------------------------------- GEMM
// C = A(MxK) @ W(KxN) + bias.  MODE 0: row-major MxN.  MODE 1: scatter to
// (B,H,T,HD) layout (BN=64 == one head per block column).
template<int MODE>
__global__ __launch_bounds__(256)
void gemm_k(const float* __restrict__ A, const float* __restrict__ W,
            const float* __restrict__ bias, float* __restrict__ C,
            int M, int N, int K)
{
    __shared__ float As[16][64];   // [k][m], col ^= (k&12)<<2
    __shared__ float Bs[16][64];   // [k][n], linear (already conflict-free)
    const int tid = threadIdx.x;
    const int tx = tid & 15, ty = tid >> 4;
    const int n0 = blockIdx.x << 6, m0 = blockIdx.y << 6;
    const int am = tid >> 2, ak = (tid & 3) << 2;   // A loader: row am, k ak..ak+3
    const int bk = tid >> 4, bn = (tid & 15) << 2;  // B loader: row bk, n bn..bn+3
    const float* Ap = A + (size_t)(m0 + am) * K + ak;
    const float* Wp = W + (size_t)bk * N + n0 + bn;

    float4 a4 = *(const float4*)(Ap);
    float4 b4 = *(const float4*)(Wp);
    float acc[4][4] = {};
    for (int k0 = 0; k0 < K; k0 += 16) {
        __syncthreads();
        {
            const int sw = (tid & 3) << 4;          // ((ak+r)&12)<<2 == ak<<2
            As[ak + 0][am ^ sw] = a4.x;
            As[ak + 1][am ^ sw] = a4.y;
            As[ak + 2][am ^ sw] = a4.z;
            As[ak + 3][am ^ sw] = a4.w;
            *(float4*)&Bs[bk][bn] = b4;
        }
        __syncthreads();
        if (k0 + 16 < K) {                           // prefetch next k-slice
            a4 = *(const float4*)(Ap + k0 + 16);
            b4 = *(const float4*)(Wp + (size_t)(k0 + 16) * N);
        }
#pragma unroll
        for (int k = 0; k < 16; ++k) {
            const float4 av = *(const float4*)&As[k][(ty << 2) ^ ((k & 12) << 2)];
            const float4 bv = *(const float4*)&Bs[k][tx << 2];
            fma16(av, bv, acc);
        }
    }
    const float4 bias4 = *(const float4*)&bias[n0 + (tx << 2)];
    const float bb[4] = {bias4.x, bias4.y, bias4.z, bias4.w};
#pragma unroll
    for (int r = 0; r < 4; ++r) {
        const int row = m0 + (ty << 2) + r;
        float4 o;
        o.x = acc[r][0] + bb[0]; o.y = acc[r][1] + bb[1];
        o.z = acc[r][2] + bb[2]; o.w = acc[r][3] + bb[3];
        if (MODE == 0) {
            *(float4*)&C[(size_t)row * N + n0 + (tx << 2)] = o;
        } else {
            const int b = row >> 11;            // row / NT
            const int i = row & (NT - 1);
            const int h = n0 >> 6;
            *(float4*)&C[((((size_t)(b * NH + h)) << 11) + i) * HD + (tx << 2)] = o;
        }
    }
}

// ---------------------------------------------------------------- windowed-sum machinery
__global__ __launch_bounds__(64)
void chunkscan_k(const float* __restrict__ g, float* __restrict__ Pin,
                 float* __restrict__ Csum)
{
    const int blk = blockIdx.x;          // bh*NCH + c
    const int lane = threadIdx.x;        // d
    const int base = (blk << 12) + lane;
    float run = 0.f;
#pragma unroll 16
    for (int t = 0; t < 64; ++t) {
        run += g[base + (t << 6)];
        Pin[base + (t << 6)] = run;
    }
    Csum[(blk << 6) + lane] = run;
}

__global__ __launch_bounds__(64)
void chunkpre_k(const float* __restrict__ Csum, float* __restrict__ Cpre)
{
    const int bh = blockIdx.x, lane = threadIdx.x;
    float run = 0.f;
    for (int c = 0; c < NCH; ++c) {
        run += Csum[((bh * NCH + c) << 6) + lane];
        Cpre[((bh * NCH + c) << 6) + lane] = run;
    }
}

__global__ __launch_bounds__(256)
void winsum_k(const float* __restrict__ Pin, const float* __restrict__ Cpre,
              float* __restrict__ wout)
{
    const int idx = blockIdx.x * 256 + threadIdx.x;   // float4 index
    const int e0 = idx << 2;
    const int row = e0 >> 6;           // bh*NT + i
    const int d = e0 & 63;
    const int bh = row >> 11;
    const int i = row & (NT - 1);
    const int c = i >> 6;

    float4 p = *(const float4*)&Pin[e0];
    float ax = p.x, ay = p.y, az = p.z, aw = p.w;
    if (c > 0) {
        const float4 q = *(const float4*)&Cpre[((bh * NCH + c - 1) << 6) + d];
        ax += q.x; ay += q.y; az += q.z; aw += q.w;
    }
    if (i >= WIN) {
        const int i2 = i - WIN;
        const int c2 = i2 >> 6;
        const float4 p2 = *(const float4*)&Pin[(((bh << 11) + i2) << 6) + d];
        ax -= p2.x; ay -= p2.y; az -= p2.z; aw -= p2.w;
        if (c2 > 0) {
            const float4 q2 = *(const float4*)&Cpre[((bh * NCH + c2 - 1) << 6) + d];
            ax -= q2.x; ay -= q2.y; az -= q2.z; aw -= q2.w;
        }
    }
    *(float4*)&wout[e0] = make_float4(ax, ay, az, aw);
}

__global__ __launch_bounds__(256)
void stats_k(float* __restrict__ wing, double* __restrict__ rowsum)
{
    const int row = (blockIdx.x << 2) + (threadIdx.x >> 6);
    const int lane = threadIdx.x & 63;
    const int i = row & (NT - 1);
    const float w = wing[(row << 6) + lane];
    const double cnt = (double)((i + 1 < WIN) ? (i + 1) : WIN);
    const double denom = (double)w / cnt + 0.5;
    double s = 1.0 / denom;
#pragma unroll
    for (int off = 32; off > 0; off >>= 1) s += __shfl_xor(s, off);
    const double gf = 1.0 / (denom * s);
    double rw = gf * (double)w;
#pragma unroll
    for (int off = 32; off > 0; off >>= 1) rw += __shfl_xor(rw, off);
    wing[(row << 6) + lane] = (float)gf;
    if (lane == 0) rowsum[row] = rw;
}

// ---------------------------------------------------------------- banded attention
// Block: one (b,h) x 64-row query tile. <=9 key tiles. S = GF.G^T, O += S.V.
// sT overlays gT. Swizzles: gfT/gT col^=(d&48); sT col^=(j&28); vsm linear.
__global__ __launch_bounds__(256)
void attn_k(const float* __restrict__ gf, const float* __restrict__ g,
            const float* __restrict__ v, const double* __restrict__ rowsum,
            float* __restrict__ outp)
{
    __shared__ float gfT[64][64];   // [d][ii ^ (d&48)]
    __shared__ float gT[64][64];    // [d][jj ^ (d&48)]  -- reused as sT[j][i^(j&28)]
    __shared__ float vsm[64][64];   // [jj][d] linear
    float (*sT)[64] = gT;

    const int bh = blockIdx.y, it = blockIdx.x;
    const int i0 = it << 6;
    const int tid = threadIdx.x;
    const int tx = tid & 15, ty = tid >> 4;
    const int ljj = tid >> 2, ld0 = (tid & 3) << 4;    // transpose loader
    const int vrow = tid >> 4, vcol = (tid & 15) << 2; // linear loader

    {   // gene_fit tile -> gfT (transposed, swizzled)
        const float* src = gf + (((size_t)(bh << 11) + i0 + ljj) << 6) + ld0;
        float4 q[4];
        q[0] = *(const float4*)(src);
        q[1] = *(const float4*)(src + 4);
        q[2] = *(const float4*)(src + 8);
        q[3] = *(const float4*)(src + 12);
        storeT(gfT, ld0, ljj, q);
    }

    const int t_lo = (it >= 8) ? (it - 8) : 0;
    float4 gq[4], vq[4];
    {   // preload first tile
        const int j0 = t_lo << 6;
        const float* gsrc = g + (((size_t)(bh << 11) + j0 + ljj) << 6) + ld0;
        const float* vsrc = v + (((size_t)(bh << 11) + j0 + vrow) << 6) + vcol;
#pragma unroll
        for (int h = 0; h < 4; ++h) gq[h] = *(const float4*)(gsrc + (h << 2));
#pragma unroll
        for (int q = 0; q < 4; ++q) vq[q] = *(const float4*)(vsrc + (size_t)(q << 10));
    }

    float acc2[4][4] = {};
    for (int t = t_lo; t <= it; ++t) {
        const int j0 = t << 6;
        __syncthreads();             // previous GEMM2 done with gT(sT)/vsm
        storeT(gT, ld0, ljj, gq);
        *(float4*)&vsm[vrow +  0][vcol] = vq[0];
        *(float4*)&vsm[vrow + 16][vcol] = vq[1];
        *(float4*)&vsm[vrow + 32][vcol] = vq[2];
        *(float4*)&vsm[vrow + 48][vcol] = vq[3];
        __syncthreads();

        if (t < it) {                // prefetch next tile (hidden under GEMMs)
            const int j1 = (t + 1) << 6;
            const float* gsrc = g + (((size_t)(bh << 11) + j1 + ljj) << 6) + ld0;
            const float* vsrc = v + (((size_t)(bh << 11) + j1 + vrow) << 6) + vcol;
#pragma unroll
            for (int h = 0; h < 4; ++h) gq[h] = *(const float4*)(gsrc + (h << 2));
#pragma unroll
            for (int q = 0; q < 4; ++q) vq[q] = *(const float4*)(vsrc + (size_t)(q << 10));
        }

        float sfr[4][4] = {};
#pragma unroll 16
        for (int k = 0; k < 64; ++k) {
            const float4 av = *(const float4*)&gfT[k][(ty << 2) ^ (k & 48)];
            const float4 bv = *(const float4*)&gT[k][(tx << 2) ^ (k & 48)];
            fma16(av, bv, sfr);
        }
        __syncthreads();             // everyone done reading gT before sT store

        const bool need_mask = (t == it) || (t == it - 8);
#pragma unroll
        for (int c = 0; c < 4; ++c) {
            float4 col = make_float4(sfr[0][c], sfr[1][c], sfr[2][c], sfr[3][c]);
            const int j = (tx << 2) + c;
            if (need_mask) {
                const int jg = j0 + j;
                const int ib = i0 + (ty << 2);
                if (!(jg <= ib + 0 && jg > ib + 0 - WIN)) col.x = 0.f;
                if (!(jg <= ib + 1 && jg > ib + 1 - WIN)) col.y = 0.f;
                if (!(jg <= ib + 2 && jg > ib + 2 - WIN)) col.z = 0.f;
                if (!(jg <= ib + 3 && jg > ib + 3 - WIN)) col.w = 0.f;
            }
            *(float4*)&sT[j][(ty << 2) ^ (j & 28)] = col;
        }
        __syncthreads();

#pragma unroll 16
        for (int k = 0; k < 64; ++k) {
            const float4 av = *(const float4*)&sT[k][(ty << 2) ^ (k & 28)];
            const float4 bv = *(const float4*)&vsm[k][tx << 2];
            fma16(av, bv, acc2);
        }
    }

    const int b = bh >> 4, h = bh & 15;
#pragma unroll
    for (int r = 0; r < 4; ++r) {
        const int i = i0 + (ty << 2) + r;
        double rs = rowsum[(bh << 11) + i];
        if (!(rs > 1e-10)) rs = 1e-10;
        const float inv = (float)(1.0 / rs);
        const float4 o = make_float4(acc2[r][0] * inv, acc2[r][1] * inv,
                                     acc2[r][2] * inv, acc2[r][3] * inv);
        *(float4*)&outp[(((size_t)(b * NT + i)) << 10) + (h << 6) + (tx << 2)] = o;
    }
}

// ---------------------------------------------------------------- launch
extern "C" void kernel_launch(void* const* d_in, const int* in_sizes, int n_in,
                              void* d_out, int out_size, void* d_ws, size_t ws_size,
                              hipStream_t stream)
{
    const float* x  = (const float*)d_in[0];
    const float* Wg = (const float*)d_in[1];
    const float* bg = (const float*)d_in[2];
    const float* Wv = (const float*)d_in[3];
    const float* bv = (const float*)d_in[4];
    const float* Wo = (const float*)d_in[5];
    const float* bo = (const float*)d_in[6];
    float* out = (float*)d_out;

    const size_t SZ = (size_t)NB * NH * NT * HD;   // 4M floats
    float* gbuf = (float*)d_ws;
    float* vbuf = gbuf + SZ;
    float* pinb = vbuf + SZ;               // chunk prefixes; later reused as attn out
    float* winb = pinb + SZ;               // winsum -> gene_fit (in place)
    float* csum = winb + SZ;               // NBH*NCH*HD = 64K floats
    float* cpre = csum + (NBH * NCH * HD);
    double* rsum = (double*)(cpre + (NBH * NCH * HD));
    float* aout = pinb;

    const int M = NB * NT;   // 4096

    gemm_k<1><<<dim3(ND >> 6, M >> 6), 256, 0, stream>>>(x, Wg, bg, gbuf, M, ND, ND);
    gemm_k<1><<<dim3(ND >> 6, M >> 6), 256, 0, stream>>>(x, Wv, bv, vbuf, M, ND, ND);
    chunkscan_k<<<NBH * NCH, 64, 0, stream>>>(gbuf, pinb, csum);
    chunkpre_k<<<NBH, 64, 0, stream>>>(csum, cpre);
    winsum_k<<<(NBH * NT * HD / 4) / 256, 256, 0, stream>>>(pinb, cpre, winb);
    stats_k<<<(NBH * NT) / 4, 256, 0, stream>>>(winb, rsum);
    attn_k<<<dim3(NT >> 6, NBH), 256, 0, stream>>>(winb, gbuf, vbuf, rsum, aout);
    gemm_k<0><<<dim3(ND >> 6, M >> 6), 256, 0, stream>>>(aout, Wo, bo, out, M, ND, ND);
}

// Round 5
// 492.843 us; speedup vs baseline: 1.2767x; 1.2767x over previous
//
#include <hip/hip_runtime.h>

#define NB 2
#define NT 2048
#define ND 1024
#define NH 16
#define HD 64
#define WIN 512
#define NBH (NB*NH)      // 32
#define NCH (NT/64)      // 32 chunks of 64 along T

typedef short    bf16x8 __attribute__((ext_vector_type(8)));
typedef unsigned short us8 __attribute__((ext_vector_type(8)));
typedef float    f32x4  __attribute__((ext_vector_type(4)));

// ---------------------------------------------------------------- helpers
__device__ __forceinline__ void fma16(const float4 av, const float4 bv, float acc[4][4])
{
    float ar[4] = {av.x, av.y, av.z, av.w};
    float br[4] = {bv.x, bv.y, bv.z, bv.w};
#pragma unroll
    for (int r = 0; r < 4; ++r)
#pragma unroll
        for (int c = 0; c < 4; ++c)
            acc[r][c] = fmaf(ar[r], br[c], acc[r][c]);
}

__device__ __forceinline__ void storeT(float (*dst)[64], int d0, int jj,
                                       const float4* q)
{
#pragma unroll
    for (int h = 0; h < 4; ++h) {
        const float vals[4] = {q[h].x, q[h].y, q[h].z, q[h].w};
#pragma unroll
        for (int r = 0; r < 4; ++r) {
            const int d = d0 + (h << 2) + r;
            dst[d][(jj ^ (d & 48))] = vals[r];
        }
    }
}

// split f into hi/lo bf16 (truncation split; residual rel err ~1.6e-5)
__device__ __forceinline__ void split_bf16(float f, unsigned short& h, unsigned short& l)
{
    unsigned u = __float_as_uint(f);
    h = (unsigned short)(u >> 16);
    float fh = __uint_as_float(u & 0xffff0000u);
    l = (unsigned short)(__float_as_uint(f - fh) >> 16);
}

// ---------------------------------------------------------------- fp32 GEMM (g-path ONLY)
// g = x@Wg+bg must stay fp32: g feeds the near-cancelling rowsum (1e-10 clamp,
// ~1e10 amplification); bf16-split would blow the error budget.
__global__ __launch_bounds__(256)
void gemm_k(const float* __restrict__ A, const float* __restrict__ W,
            const float* __restrict__ bias, float* __restrict__ C,
            int M, int N, int K)
{
    __shared__ float As[16][64];   // [k][m], col ^= (k&12)<<2
    __shared__ float Bs[16][64];   // [k][n]
    const int tid = threadIdx.x;
    const int tx = tid & 15, ty = tid >> 4;
    const int n0 = blockIdx.x << 6, m0 = blockIdx.y << 6;
    const int am = tid >> 2, ak = (tid & 3) << 2;
    const int bk = tid >> 4, bn = (tid & 15) << 2;
    const float* Ap = A + (size_t)(m0 + am) * K + ak;
    const float* Wp = W + (size_t)bk * N + n0 + bn;

    float4 a4 = *(const float4*)(Ap);
    float4 b4 = *(const float4*)(Wp);
    float acc[4][4] = {};
    for (int k0 = 0; k0 < K; k0 += 16) {
        __syncthreads();
        {
            const int sw = (tid & 3) << 4;
            As[ak + 0][am ^ sw] = a4.x;
            As[ak + 1][am ^ sw] = a4.y;
            As[ak + 2][am ^ sw] = a4.z;
            As[ak + 3][am ^ sw] = a4.w;
            *(float4*)&Bs[bk][bn] = b4;
        }
        __syncthreads();
        if (k0 + 16 < K) {
            a4 = *(const float4*)(Ap + k0 + 16);
            b4 = *(const float4*)(Wp + (size_t)(k0 + 16) * N);
        }
#pragma unroll
        for (int k = 0; k < 16; ++k) {
            const float4 av = *(const float4*)&As[k][(ty << 2) ^ ((k & 12) << 2)];
            const float4 bv = *(const float4*)&Bs[k][tx << 2];
            fma16(av, bv, acc);
        }
    }
    const float4 bias4 = *(const float4*)&bias[n0 + (tx << 2)];
    const float bb[4] = {bias4.x, bias4.y, bias4.z, bias4.w};
#pragma unroll
    for (int r = 0; r < 4; ++r) {
        const int row = m0 + (ty << 2) + r;
        float4 o;
        o.x = acc[r][0] + bb[0]; o.y = acc[r][1] + bb[1];
        o.z = acc[r][2] + bb[2]; o.w = acc[r][3] + bb[3];
        const int b = row >> 11;
        const int i = row & (NT - 1);
        const int h = n0 >> 6;
        *(float4*)&C[((((size_t)(b * NH + h)) << 11) + i) * HD + (tx << 2)] = o;
    }
}

// ---------------------------------------------------------------- bf16x2 MFMA GEMM
// C = A(MxK) @ B(KxN) + bias, A/B pre-split into hi/lo bf16 planes.
// A planes: [m][k] row-major. B planes: [n][k] (pre-transposed). 3 MFMA
// passes: hi*hi + hi*lo + lo*hi (lo*lo dropped, rel ~1.6e-5).
// Tile 128x128xBK32, 4 waves (2x2 of 64x64), 16x16x32 MFMA.
// LDS rows of 32 bf16 = 4 slots of 16B; slot ^= (r&3)^((r>>2)&3).
template<int MODE>  // 0: row-major out; 1: scatter to (B,H,T,HD)
__global__ __launch_bounds__(256)
void mgemm_k(const unsigned short* __restrict__ Ahi, const unsigned short* __restrict__ Alo,
             const unsigned short* __restrict__ Bhi, const unsigned short* __restrict__ Blo,
             const float* __restrict__ bias, float* __restrict__ C,
             int M, int N, int K)
{
    __shared__ unsigned short As[2][128 * 32];
    __shared__ unsigned short Bs[2][128 * 32];
    const int tid = threadIdx.x;
    const int wave = tid >> 6, lane = tid & 63;
    const int wm = wave >> 1, wn = wave & 1;
    const int m0 = blockIdx.y << 7, n0 = blockIdx.x << 7;

    const int srow = tid >> 1, skh = tid & 1;
    const int ssw = (srow & 3) ^ ((srow >> 2) & 3);
    const int sA0 = srow * 32 + ((((skh << 1) | 0) ^ ssw) << 3);
    const int sA1 = srow * 32 + ((((skh << 1) | 1) ^ ssw) << 3);
    const size_t aoff = (size_t)(m0 + srow) * K + (skh << 4);
    const size_t boff = (size_t)(n0 + srow) * K + (skh << 4);

    us8 ah0 = *(const us8*)(Ahi + aoff), ah1 = *(const us8*)(Ahi + aoff + 8);
    us8 al0 = *(const us8*)(Alo + aoff), al1 = *(const us8*)(Alo + aoff + 8);
    us8 bh0 = *(const us8*)(Bhi + boff), bh1 = *(const us8*)(Bhi + boff + 8);
    us8 bl0 = *(const us8*)(Blo + boff), bl1 = *(const us8*)(Blo + boff + 8);

    const int fsw = ((lane >> 4) ^ (lane & 3) ^ ((lane & 12) >> 2)) << 3;

    f32x4 acc[4][4] = {};
    for (int k0 = 0; k0 < K; k0 += 32) {
        __syncthreads();
        *(us8*)&As[0][sA0] = ah0; *(us8*)&As[0][sA1] = ah1;
        *(us8*)&As[1][sA0] = al0; *(us8*)&As[1][sA1] = al1;
        *(us8*)&Bs[0][sA0] = bh0; *(us8*)&Bs[0][sA1] = bh1;
        *(us8*)&Bs[1][sA0] = bl0; *(us8*)&Bs[1][sA1] = bl1;
        __syncthreads();
        if (k0 + 32 < K) {
            const size_t ka = aoff + k0 + 32, kb = boff + k0 + 32;
            ah0 = *(const us8*)(Ahi + ka); ah1 = *(const us8*)(Ahi + ka + 8);
            al0 = *(const us8*)(Alo + ka); al1 = *(const us8*)(Alo + ka + 8);
            bh0 = *(const us8*)(Bhi + kb); bh1 = *(const us8*)(Bhi + kb + 8);
            bl0 = *(const us8*)(Blo + kb); bl1 = *(const us8*)(Blo + kb + 8);
        }
        bf16x8 aH[4], aL[4], bH[4], bL[4];
#pragma unroll
        for (int s = 0; s < 4; ++s) {
            const int ra = (wm << 6) + (s << 4) + (lane & 15);
            const int rb = (wn << 6) + (s << 4) + (lane & 15);
            aH[s] = *(const bf16x8*)&As[0][ra * 32 + fsw];
            aL[s] = *(const bf16x8*)&As[1][ra * 32 + fsw];
            bH[s] = *(const bf16x8*)&Bs[0][rb * 32 + fsw];
            bL[s] = *(const bf16x8*)&Bs[1][rb * 32 + fsw];
        }
#pragma unroll
        for (int ms = 0; ms < 4; ++ms)
#pragma unroll
            for (int ns = 0; ns < 4; ++ns) {
                acc[ms][ns] = __builtin_amdgcn_mfma_f32_16x16x32_bf16(aH[ms], bH[ns], acc[ms][ns], 0, 0, 0);
                acc[ms][ns] = __builtin_amdgcn_mfma_f32_16x16x32_bf16(aH[ms], bL[ns], acc[ms][ns], 0, 0, 0);
                acc[ms][ns] = __builtin_amdgcn_mfma_f32_16x16x32_bf16(aL[ms], bH[ns], acc[ms][ns], 0, 0, 0);
            }
    }

    // epilogue: C layout col=lane&15, row=(lane>>4)*4+reg  [verified m89]
#pragma unroll
    for (int ms = 0; ms < 4; ++ms)
#pragma unroll
        for (int ns = 0; ns < 4; ++ns) {
            const int col = n0 + (wn << 6) + (ns << 4) + (lane & 15);
            const float bb = bias[col];
#pragma unroll
            for (int r = 0; r < 4; ++r) {
                const int row = m0 + (wm << 6) + (ms << 4) + ((lane >> 4) << 2) + r;
                const float val = acc[ms][ns][r] + bb;
                if (MODE == 0) {
                    C[(size_t)row * N + col] = val;
                } else {
                    const int b = row >> 11, i = row & (NT - 1);
                    const int h = col >> 6;
                    C[((((size_t)(b * NH + h)) << 11) + i) * HD + (col & 63)] = val;
                }
            }
        }
}

// ---------------------------------------------------------------- prep kernels
__global__ __launch_bounds__(256)
void split_k(const float* __restrict__ x, unsigned short* __restrict__ xh,
             unsigned short* __restrict__ xl)
{
    const int e0 = (blockIdx.x * 256 + threadIdx.x) << 2;
    const float4 v = *(const float4*)&x[e0];
    ushort4 hh, ll;
    split_bf16(v.x, hh.x, ll.x); split_bf16(v.y, hh.y, ll.y);
    split_bf16(v.z, hh.z, ll.z); split_bf16(v.w, hh.w, ll.w);
    *(ushort4*)&xh[e0] = hh;
    *(ushort4*)&xl[e0] = ll;
}

// W [k][n] fp32 -> WT [n][k] hi/lo bf16 planes. Ls padded to 68 floats/row:
// 272B stride keeps every float4 LDS access 16B-aligned (65 was misaligned
// -> ds_write_b128 align-down corruption, the Round-4 bug).
__global__ __launch_bounds__(256)
void tsplit_k(const float* __restrict__ W, unsigned short* __restrict__ Th,
              unsigned short* __restrict__ Tl)
{
    __shared__ float Ls[64][68];
    const int n0 = blockIdx.x << 6, k0 = blockIdx.y << 6;
    const int tid = threadIdx.x;
    const int r16 = tid >> 4, c4 = (tid & 15) << 2;
#pragma unroll
    for (int j = 0; j < 4; ++j) {
        const int row = r16 + (j << 4);
        *(float4*)&Ls[row][c4] = *(const float4*)&W[(size_t)(k0 + row) * ND + n0 + c4];
    }
    __syncthreads();
#pragma unroll
    for (int j = 0; j < 4; ++j) {
        const int n = r16 + (j << 4);
        ushort4 hh, ll;
        split_bf16(Ls[c4 + 0][n], hh.x, ll.x);
        split_bf16(Ls[c4 + 1][n], hh.y, ll.y);
        split_bf16(Ls[c4 + 2][n], hh.z, ll.z);
        split_bf16(Ls[c4 + 3][n], hh.w, ll.w);
        const size_t o = (size_t)(n0 + n) * ND + k0 + c4;
        *(ushort4*)&Th[o] = hh;
        *(ushort4*)&Tl[o] = ll;
    }
}

// ---------------------------------------------------------------- windowed-sum machinery
__global__ __launch_bounds__(64)
void chunkscan_k(const float* __restrict__ g, float* __restrict__ Pin,
                 float* __restrict__ Csum)
{
    const int blk = blockIdx.x;
    const int lane = threadIdx.x;
    const int base = (blk << 12) + lane;
    float run = 0.f;
#pragma unroll 16
    for (int t = 0; t < 64; ++t) {
        run += g[base + (t << 6)];
        Pin[base + (t << 6)] = run;
    }
    Csum[(blk << 6) + lane] = run;
}

__global__ __launch_bounds__(64)
void chunkpre_k(const float* __restrict__ Csum, float* __restrict__ Cpre)
{
    const int bh = blockIdx.x, lane = threadIdx.x;
    float run = 0.f;
    for (int c = 0; c < NCH; ++c) {
        run += Csum[((bh * NCH + c) << 6) + lane];
        Cpre[((bh * NCH + c) << 6) + lane] = run;
    }
}

__global__ __launch_bounds__(256)
void winsum_k(const float* __restrict__ Pin, const float* __restrict__ Cpre,
              float* __restrict__ wout)
{
    const int idx = blockIdx.x * 256 + threadIdx.x;
    const int e0 = idx << 2;
    const int row = e0 >> 6;
    const int d = e0 & 63;
    const int bh = row >> 11;
    const int i = row & (NT - 1);
    const int c = i >> 6;

    float4 p = *(const float4*)&Pin[e0];
    float ax = p.x, ay = p.y, az = p.z, aw = p.w;
    if (c > 0) {
        const float4 q = *(const float4*)&Cpre[((bh * NCH + c - 1) << 6) + d];
        ax += q.x; ay += q.y; az += q.z; aw += q.w;
    }
    if (i >= WIN) {
        const int i2 = i - WIN;
        const int c2 = i2 >> 6;
        const float4 p2 = *(const float4*)&Pin[(((bh << 11) + i2) << 6) + d];
        ax -= p2.x; ay -= p2.y; az -= p2.z; aw -= p2.w;
        if (c2 > 0) {
            const float4 q2 = *(const float4*)&Cpre[((bh * NCH + c2 - 1) << 6) + d];
            ax -= q2.x; ay -= q2.y; az -= q2.z; aw -= q2.w;
        }
    }
    *(float4*)&wout[e0] = make_float4(ax, ay, az, aw);
}

__global__ __launch_bounds__(256)
void stats_k(float* __restrict__ wing, double* __restrict__ rowsum)
{
    const int row = (blockIdx.x << 2) + (threadIdx.x >> 6);
    const int lane = threadIdx.x & 63;
    const int i = row & (NT - 1);
    const float w = wing[(row << 6) + lane];
    const double cnt = (double)((i + 1 < WIN) ? (i + 1) : WIN);
    const double denom = (double)w / cnt + 0.5;
    double s = 1.0 / denom;
#pragma unroll
    for (int off = 32; off > 0; off >>= 1) s += __shfl_xor(s, off);
    const double gf = 1.0 / (denom * s);
    double rw = gf * (double)w;
#pragma unroll
    for (int off = 32; off > 0; off >>= 1) rw += __shfl_xor(rw, off);
    wing[(row << 6) + lane] = (float)gf;
    if (lane == 0) rowsum[row] = rw;
}

// ---------------------------------------------------------------- banded attention
__global__ __launch_bounds__(256)
void attn_k(const float* __restrict__ gf, const float* __restrict__ g,
            const float* __restrict__ v, const double* __restrict__ rowsum,
            unsigned short* __restrict__ aoh, unsigned short* __restrict__ aol)
{
    __shared__ float gfT[64][64];
    __shared__ float gT[64][64];
    __shared__ float vsm[64][64];
    float (*sT)[64] = gT;

    const int bh = blockIdx.y, it = blockIdx.x;
    const int i0 = it << 6;
    const int tid = threadIdx.x;
    const int tx = tid & 15, ty = tid >> 4;
    const int ljj = tid >> 2, ld0 = (tid & 3) << 4;
    const int vrow = tid >> 4, vcol = (tid & 15) << 2;

    {
        const float* src = gf + (((size_t)(bh << 11) + i0 + ljj) << 6) + ld0;
        float4 q[4];
        q[0] = *(const float4*)(src);
        q[1] = *(const float4*)(src + 4);
        q[2] = *(const float4*)(src + 8);
        q[3] = *(const float4*)(src + 12);
        storeT(gfT, ld0, ljj, q);
    }

    const int t_lo = (it >= 8) ? (it - 8) : 0;
    float4 gq[4], vq[4];
    {
        const int j0 = t_lo << 6;
        const float* gsrc = g + (((size_t)(bh << 11) + j0 + ljj) << 6) + ld0;
        const float* vsrc = v + (((size_t)(bh << 11) + j0 + vrow) << 6) + vcol;
#pragma unroll
        for (int h = 0; h < 4; ++h) gq[h] = *(const float4*)(gsrc + (h << 2));
#pragma unroll
        for (int q = 0; q < 4; ++q) vq[q] = *(const float4*)(vsrc + (size_t)(q << 10));
    }

    float acc2[4][4] = {};
    for (int t = t_lo; t <= it; ++t) {
        const int j0 = t << 6;
        __syncthreads();
        storeT(gT, ld0, ljj, gq);
        *(float4*)&vsm[vrow +  0][vcol] = vq[0];
        *(float4*)&vsm[vrow + 16][vcol] = vq[1];
        *(float4*)&vsm[vrow + 32][vcol] = vq[2];
        *(float4*)&vsm[vrow + 48][vcol] = vq[3];
        __syncthreads();

        if (t < it) {
            const int j1 = (t + 1) << 6;
            const float* gsrc = g + (((size_t)(bh << 11) + j1 + ljj) << 6) + ld0;
            const float* vsrc = v + (((size_t)(bh << 11) + j1 + vrow) << 6) + vcol;
#pragma unroll
            for (int h = 0; h < 4; ++h) gq[h] = *(const float4*)(gsrc + (h << 2));
#pragma unroll
            for (int q = 0; q < 4; ++q) vq[q] = *(const float4*)(vsrc + (size_t)(q << 10));
        }

        float sfr[4][4] = {};
#pragma unroll 16
        for (int k = 0; k < 64; ++k) {
            const float4 av = *(const float4*)&gfT[k][(ty << 2) ^ (k & 48)];
            const float4 bv = *(const float4*)&gT[k][(tx << 2) ^ (k & 48)];
            fma16(av, bv, sfr);
        }
        __syncthreads();

        const bool need_mask = (t == it) || (t == it - 8);
#pragma unroll
        for (int c = 0; c < 4; ++c) {
            float4 col = make_float4(sfr[0][c], sfr[1][c], sfr[2][c], sfr[3][c]);
            const int j = (tx << 2) + c;
            if (need_mask) {
                const int jg = j0 + j;
                const int ib = i0 + (ty << 2);
                if (!(jg <= ib + 0 && jg > ib + 0 - WIN)) col.x = 0.f;
                if (!(jg <= ib + 1 && jg > ib + 1 - WIN)) col.y = 0.f;
                if (!(jg <= ib + 2 && jg > ib + 2 - WIN)) col.z = 0.f;
                if (!(jg <= ib + 3 && jg > ib + 3 - WIN)) col.w = 0.f;
            }
            *(float4*)&sT[j][(ty << 2) ^ (j & 28)] = col;
        }
        __syncthreads();

#pragma unroll 16
        for (int k = 0; k < 64; ++k) {
            const float4 av = *(const float4*)&sT[k][(ty << 2) ^ (k & 28)];
            const float4 bv = *(const float4*)&vsm[k][tx << 2];
            fma16(av, bv, acc2);
        }
    }

    const int b = bh >> 4, hh = bh & 15;
#pragma unroll
    for (int r = 0; r < 4; ++r) {
        const int i = i0 + (ty << 2) + r;
        double rs = rowsum[(bh << 11) + i];
        if (!(rs > 1e-10)) rs = 1e-10;
        const float inv = (float)(1.0 / rs);
        const float o[4] = {acc2[r][0] * inv, acc2[r][1] * inv,
                            acc2[r][2] * inv, acc2[r][3] * inv};
        ushort4 oh, ol;
        split_bf16(o[0], oh.x, ol.x); split_bf16(o[1], oh.y, ol.y);
        split_bf16(o[2], oh.z, ol.z); split_bf16(o[3], oh.w, ol.w);
        const size_t base = (((size_t)(b * NT + i)) << 10) + (hh << 6) + (tx << 2);
        *(ushort4*)&aoh[base] = oh;
        *(ushort4*)&aol[base] = ol;
    }
}

// ---------------------------------------------------------------- launch
// Workspace map (73 MB, live ranges disjoint where overlaid):
//   gbuf  [SZ]      g        (gemm -> attn)
//   vbuf  [SZ]      v        (mgemm<1> -> attn)
//   pinb  [SZ]      prefixes (chunkscan -> winsum), then aoh/aol (attn -> mgemm<0>)
//   winb  [SZ]      xhi/xlo  (split_k -> mgemm<1>), then gene_fit (winsum -> attn)
//   wpl   [2*MW]    4 ushort W planes (tsplit -> mgemm<0>)
//   csum/cpre/rsum  dedicated tail (Round-4 bug: these previously overlapped wpl)
extern "C" void kernel_launch(void* const* d_in, const int* in_sizes, int n_in,
                              void* d_out, int out_size, void* d_ws, size_t ws_size,
                              hipStream_t stream)
{
    const float* x  = (const float*)d_in[0];
    const float* Wg = (const float*)d_in[1];
    const float* bg = (const float*)d_in[2];
    const float* Wv = (const float*)d_in[3];
    const float* bv = (const float*)d_in[4];
    const float* Wo = (const float*)d_in[5];
    const float* bo = (const float*)d_in[6];
    float* out = (float*)d_out;

    const size_t SZ = (size_t)NB * NH * NT * HD;   // 4M floats
    const size_t MW = (size_t)ND * ND;             // 1M
    const size_t CS = (size_t)NBH * NCH * HD;      // 64K

    float* gbuf = (float*)d_ws;
    float* vbuf = gbuf + SZ;
    float* pinb = vbuf + SZ;
    float* winb = pinb + SZ;
    float* wpl  = winb + SZ;
    float* csum = wpl + 2 * MW;            // 4 ushort planes = 2*MW floats
    float* cpre = csum + CS;
    double* rsum = (double*)(cpre + CS);

    unsigned short* xhi  = (unsigned short*)winb;
    unsigned short* xlo  = xhi + SZ;
    unsigned short* wvTh = (unsigned short*)wpl;
    unsigned short* wvTl = wvTh + MW;
    unsigned short* woTh = wvTl + MW;
    unsigned short* woTl = woTh + MW;
    unsigned short* aoh  = (unsigned short*)pinb;
    unsigned short* aol  = aoh + SZ;

    const int M = NB * NT;   // 4096

    gemm_k<<<dim3(ND >> 6, M >> 6), 256, 0, stream>>>(x, Wg, bg, gbuf, M, ND, ND);
    split_k<<<(int)(SZ / 4 / 256), 256, 0, stream>>>(x, xhi, xlo);
    tsplit_k<<<dim3(ND >> 6, ND >> 6), 256, 0, stream>>>(Wv, wvTh, wvTl);
    tsplit_k<<<dim3(ND >> 6, ND >> 6), 256, 0, stream>>>(Wo, woTh, woTl);
    mgemm_k<1><<<dim3(ND >> 7, M >> 7), 256, 0, stream>>>(xhi, xlo, wvTh, wvTl, bv, vbuf, M, ND, ND);
    chunkscan_k<<<NBH * NCH, 64, 0, stream>>>(gbuf, pinb, csum);
    chunkpre_k<<<NBH, 64, 0, stream>>>(csum, cpre);
    winsum_k<<<(NBH * NT * HD / 4) / 256, 256, 0, stream>>>(pinb, cpre, winb);
    stats_k<<<(NBH * NT) / 4, 256, 0, stream>>>(winb, rsum);
    attn_k<<<dim3(NT >> 6, NBH), 256, 0, stream>>>(winb, gbuf, vbuf, rsum, aoh, aol);
    mgemm_k<0><<<dim3(ND >> 7, M >> 7), 256, 0, stream>>>(aoh, aol, woTh, woTl, bo, out, M, ND, ND);
}

// Round 7
// 388.727 us; speedup vs baseline: 1.6186x; 1.2678x over previous
//
#include <hip/hip_runtime.h>

#define NB 2
#define NT 2048
#define ND 1024
#define NH 16
#define HD 64
#define WIN 512
#define NBH (NB*NH)      // 32
#define NCH (NT/64)      // 32 chunks of 64 along T

typedef short    bf16x8 __attribute__((ext_vector_type(8)));
typedef unsigned short us8 __attribute__((ext_vector_type(8)));
typedef unsigned short us4 __attribute__((ext_vector_type(4)));
typedef float    f32x4  __attribute__((ext_vector_type(4)));

// ---------------------------------------------------------------- helpers
__device__ __forceinline__ void fma16(const float4 av, const float4 bv, float acc[4][4])
{
    float ar[4] = {av.x, av.y, av.z, av.w};
    float br[4] = {bv.x, bv.y, bv.z, bv.w};
#pragma unroll
    for (int r = 0; r < 4; ++r)
#pragma unroll
        for (int c = 0; c < 4; ++c)
            acc[r][c] = fmaf(ar[r], br[c], acc[r][c]);
}

// split f into hi/lo bf16 (truncation split; residual rel err ~1.6e-5)
__device__ __forceinline__ void split_bf16(float f, unsigned short& h, unsigned short& l)
{
    unsigned u = __float_as_uint(f);
    h = (unsigned short)(u >> 16);
    float fh = __uint_as_float(u & 0xffff0000u);
    l = (unsigned short)(__float_as_uint(f - fh) >> 16);
}

// fp32 -> bf16 round-to-nearest-even
__device__ __forceinline__ unsigned short bf_rne(float f)
{
    unsigned u = __float_as_uint(f);
    u += 0x7fffu + ((u >> 16) & 1u);
    return (unsigned short)(u >> 16);
}

__device__ __forceinline__ us8 pack8(float4 a, float4 b)
{
    us8 r;
    r[0] = bf_rne(a.x); r[1] = bf_rne(a.y); r[2] = bf_rne(a.z); r[3] = bf_rne(a.w);
    r[4] = bf_rne(b.x); r[5] = bf_rne(b.y); r[6] = bf_rne(b.z); r[7] = bf_rne(b.w);
    return r;
}

// ---------------------------------------------------------------- fp32 GEMM (g-path ONLY)
// g = x@Wg+bg must stay fp32: g feeds the near-cancelling rowsum (1e-10 clamp,
// ~1e10 amplification); winsum abs-err must stay ~1e-6 (bf16x2 would give 2e-4).
__global__ __launch_bounds__(256)
void gemm_k(const float* __restrict__ A, const float* __restrict__ W,
            const float* __restrict__ bias, float* __restrict__ C,
            int M, int N, int K)
{
    __shared__ float As[16][64];   // [k][m], col ^= (k&12)<<2
    __shared__ float Bs[16][64];   // [k][n]
    const int tid = threadIdx.x;
    const int tx = tid & 15, ty = tid >> 4;
    const int n0 = blockIdx.x << 6, m0 = blockIdx.y << 6;
    const int am = tid >> 2, ak = (tid & 3) << 2;
    const int bk = tid >> 4, bn = (tid & 15) << 2;
    const float* Ap = A + (size_t)(m0 + am) * K + ak;
    const float* Wp = W + (size_t)bk * N + n0 + bn;

    float4 a4 = *(const float4*)(Ap);
    float4 b4 = *(const float4*)(Wp);
    float acc[4][4] = {};
    for (int k0 = 0; k0 < K; k0 += 16) {
        __syncthreads();
        {
            const int sw = (tid & 3) << 4;
            As[ak + 0][am ^ sw] = a4.x;
            As[ak + 1][am ^ sw] = a4.y;
            As[ak + 2][am ^ sw] = a4.z;
            As[ak + 3][am ^ sw] = a4.w;
            *(float4*)&Bs[bk][bn] = b4;
        }
        __syncthreads();
        if (k0 + 16 < K) {
            a4 = *(const float4*)(Ap + k0 + 16);
            b4 = *(const float4*)(Wp + (size_t)(k0 + 16) * N);
        }
#pragma unroll
        for (int k = 0; k < 16; ++k) {
            const float4 av = *(const float4*)&As[k][(ty << 2) ^ ((k & 12) << 2)];
            const float4 bv = *(const float4*)&Bs[k][tx << 2];
            fma16(av, bv, acc);
        }
    }
    const float4 bias4 = *(const float4*)&bias[n0 + (tx << 2)];
    const float bb[4] = {bias4.x, bias4.y, bias4.z, bias4.w};
#pragma unroll
    for (int r = 0; r < 4; ++r) {
        const int row = m0 + (ty << 2) + r;
        float4 o;
        o.x = acc[r][0] + bb[0]; o.y = acc[r][1] + bb[1];
        o.z = acc[r][2] + bb[2]; o.w = acc[r][3] + bb[3];
        const int b = row >> 11;
        const int i = row & (NT - 1);
        const int h = n0 >> 6;
        *(float4*)&C[((((size_t)(b * NH + h)) << 11) + i) * HD + (tx << 2)] = o;
    }
}

// ---------------------------------------------------------------- bf16x2 MFMA GEMM
template<int MODE>  // 0: row-major out; 1: scatter to (B,H,T,HD)
__global__ __launch_bounds__(256)
void mgemm_k(const unsigned short* __restrict__ Ahi, const unsigned short* __restrict__ Alo,
             const unsigned short* __restrict__ Bhi, const unsigned short* __restrict__ Blo,
             const float* __restrict__ bias, float* __restrict__ C,
             int M, int N, int K)
{
    __shared__ unsigned short As[2][128 * 32];
    __shared__ unsigned short Bs[2][128 * 32];
    const int tid = threadIdx.x;
    const int wave = tid >> 6, lane = tid & 63;
    const int wm = wave >> 1, wn = wave & 1;
    const int m0 = blockIdx.y << 7, n0 = blockIdx.x << 7;

    const int srow = tid >> 1, skh = tid & 1;
    const int ssw = (srow & 3) ^ ((srow >> 2) & 3);
    const int sA0 = srow * 32 + ((((skh << 1) | 0) ^ ssw) << 3);
    const int sA1 = srow * 32 + ((((skh << 1) | 1) ^ ssw) << 3);
    const size_t aoff = (size_t)(m0 + srow) * K + (skh << 4);
    const size_t boff = (size_t)(n0 + srow) * K + (skh << 4);

    us8 ah0 = *(const us8*)(Ahi + aoff), ah1 = *(const us8*)(Ahi + aoff + 8);
    us8 al0 = *(const us8*)(Alo + aoff), al1 = *(const us8*)(Alo + aoff + 8);
    us8 bh0 = *(const us8*)(Bhi + boff), bh1 = *(const us8*)(Bhi + boff + 8);
    us8 bl0 = *(const us8*)(Blo + boff), bl1 = *(const us8*)(Blo + boff + 8);

    const int fsw = ((lane >> 4) ^ (lane & 3) ^ ((lane & 12) >> 2)) << 3;

    f32x4 acc[4][4] = {};
    for (int k0 = 0; k0 < K; k0 += 32) {
        __syncthreads();
        *(us8*)&As[0][sA0] = ah0; *(us8*)&As[0][sA1] = ah1;
        *(us8*)&As[1][sA0] = al0; *(us8*)&As[1][sA1] = al1;
        *(us8*)&Bs[0][sA0] = bh0; *(us8*)&Bs[0][sA1] = bh1;
        *(us8*)&Bs[1][sA0] = bl0; *(us8*)&Bs[1][sA1] = bl1;
        __syncthreads();
        if (k0 + 32 < K) {
            const size_t ka = aoff + k0 + 32, kb = boff + k0 + 32;
            ah0 = *(const us8*)(Ahi + ka); ah1 = *(const us8*)(Ahi + ka + 8);
            al0 = *(const us8*)(Alo + ka); al1 = *(const us8*)(Alo + ka + 8);
            bh0 = *(const us8*)(Bhi + kb); bh1 = *(const us8*)(Bhi + kb + 8);
            bl0 = *(const us8*)(Blo + kb); bl1 = *(const us8*)(Blo + kb + 8);
        }
        bf16x8 aH[4], aL[4], bH[4], bL[4];
#pragma unroll
        for (int s = 0; s < 4; ++s) {
            const int ra = (wm << 6) + (s << 4) + (lane & 15);
            const int rb = (wn << 6) + (s << 4) + (lane & 15);
            aH[s] = *(const bf16x8*)&As[0][ra * 32 + fsw];
            aL[s] = *(const bf16x8*)&As[1][ra * 32 + fsw];
            bH[s] = *(const bf16x8*)&Bs[0][rb * 32 + fsw];
            bL[s] = *(const bf16x8*)&Bs[1][rb * 32 + fsw];
        }
#pragma unroll
        for (int ms = 0; ms < 4; ++ms)
#pragma unroll
            for (int ns = 0; ns < 4; ++ns) {
                acc[ms][ns] = __builtin_amdgcn_mfma_f32_16x16x32_bf16(aH[ms], bH[ns], acc[ms][ns], 0, 0, 0);
                acc[ms][ns] = __builtin_amdgcn_mfma_f32_16x16x32_bf16(aH[ms], bL[ns], acc[ms][ns], 0, 0, 0);
                acc[ms][ns] = __builtin_amdgcn_mfma_f32_16x16x32_bf16(aL[ms], bH[ns], acc[ms][ns], 0, 0, 0);
            }
    }

#pragma unroll
    for (int ms = 0; ms < 4; ++ms)
#pragma unroll
        for (int ns = 0; ns < 4; ++ns) {
            const int col = n0 + (wn << 6) + (ns << 4) + (lane & 15);
            const float bb = bias[col];
#pragma unroll
            for (int r = 0; r < 4; ++r) {
                const int row = m0 + (wm << 6) + (ms << 4) + ((lane >> 4) << 2) + r;
                const float val = acc[ms][ns][r] + bb;
                if (MODE == 0) {
                    C[(size_t)row * N + col] = val;
                } else {
                    const int b = row >> 11, i = row & (NT - 1);
                    const int h = col >> 6;
                    C[((((size_t)(b * NH + h)) << 11) + i) * HD + (col & 63)] = val;
                }
            }
        }
}

// ---------------------------------------------------------------- prep kernels
__global__ __launch_bounds__(256)
void split_k(const float* __restrict__ x, unsigned short* __restrict__ xh,
             unsigned short* __restrict__ xl)
{
    const int e0 = (blockIdx.x * 256 + threadIdx.x) << 2;
    const float4 v = *(const float4*)&x[e0];
    ushort4 hh, ll;
    split_bf16(v.x, hh.x, ll.x); split_bf16(v.y, hh.y, ll.y);
    split_bf16(v.z, hh.z, ll.z); split_bf16(v.w, hh.w, ll.w);
    *(ushort4*)&xh[e0] = hh;
    *(ushort4*)&xl[e0] = ll;
}

// W [k][n] fp32 -> WT [n][k] hi/lo bf16 planes. 68-float row stride keeps
// float4 LDS ops 16B-aligned.
__global__ __launch_bounds__(256)
void tsplit_k(const float* __restrict__ W, unsigned short* __restrict__ Th,
              unsigned short* __restrict__ Tl)
{
    __shared__ float Ls[64][68];
    const int n0 = blockIdx.x << 6, k0 = blockIdx.y << 6;
    const int tid = threadIdx.x;
    const int r16 = tid >> 4, c4 = (tid & 15) << 2;
#pragma unroll
    for (int j = 0; j < 4; ++j) {
        const int row = r16 + (j << 4);
        *(float4*)&Ls[row][c4] = *(const float4*)&W[(size_t)(k0 + row) * ND + n0 + c4];
    }
    __syncthreads();
#pragma unroll
    for (int j = 0; j < 4; ++j) {
        const int n = r16 + (j << 4);
        ushort4 hh, ll;
        split_bf16(Ls[c4 + 0][n], hh.x, ll.x);
        split_bf16(Ls[c4 + 1][n], hh.y, ll.y);
        split_bf16(Ls[c4 + 2][n], hh.z, ll.z);
        split_bf16(Ls[c4 + 3][n], hh.w, ll.w);
        const size_t o = (size_t)(n0 + n) * ND + k0 + c4;
        *(ushort4*)&Th[o] = hh;
        *(ushort4*)&Tl[o] = ll;
    }
}

// ---------------------------------------------------------------- windowed-sum machinery
__global__ __launch_bounds__(64)
void chunkscan_k(const float* __restrict__ g, float* __restrict__ Pin,
                 float* __restrict__ Csum)
{
    const int blk = blockIdx.x;
    const int lane = threadIdx.x;
    const int base = (blk << 12) + lane;
    float run = 0.f;
#pragma unroll 16
    for (int t = 0; t < 64; ++t) {
        run += g[base + (t << 6)];
        Pin[base + (t << 6)] = run;
    }
    Csum[(blk << 6) + lane] = run;
}

__global__ __launch_bounds__(64)
void chunkpre_k(const float* __restrict__ Csum, float* __restrict__ Cpre)
{
    const int bh = blockIdx.x, lane = threadIdx.x;
    float run = 0.f;
    for (int c = 0; c < NCH; ++c) {
        run += Csum[((bh * NCH + c) << 6) + lane];
        Cpre[((bh * NCH + c) << 6) + lane] = run;
    }
}

__global__ __launch_bounds__(256)
void winsum_k(const float* __restrict__ Pin, const float* __restrict__ Cpre,
              float* __restrict__ wout)
{
    const int idx = blockIdx.x * 256 + threadIdx.x;
    const int e0 = idx << 2;
    const int row = e0 >> 6;
    const int d = e0 & 63;
    const int bh = row >> 11;
    const int i = row & (NT - 1);
    const int c = i >> 6;

    float4 p = *(const float4*)&Pin[e0];
    float ax = p.x, ay = p.y, az = p.z, aw = p.w;
    if (c > 0) {
        const float4 q = *(const float4*)&Cpre[((bh * NCH + c - 1) << 6) + d];
        ax += q.x; ay += q.y; az += q.z; aw += q.w;
    }
    if (i >= WIN) {
        const int i2 = i - WIN;
        const int c2 = i2 >> 6;
        const float4 p2 = *(const float4*)&Pin[(((bh << 11) + i2) << 6) + d];
        ax -= p2.x; ay -= p2.y; az -= p2.z; aw -= p2.w;
        if (c2 > 0) {
            const float4 q2 = *(const float4*)&Cpre[((bh * NCH + c2 - 1) << 6) + d];
            ax -= q2.x; ay -= q2.y; az -= q2.z; aw -= q2.w;
        }
    }
    *(float4*)&wout[e0] = make_float4(ax, ay, az, aw);
}

__global__ __launch_bounds__(256)
void stats_k(float* __restrict__ wing, double* __restrict__ rowsum)
{
    const int row = (blockIdx.x << 2) + (threadIdx.x >> 6);
    const int lane = threadIdx.x & 63;
    const int i = row & (NT - 1);
    const float w = wing[(row << 6) + lane];
    const double cnt = (double)((i + 1 < WIN) ? (i + 1) : WIN);
    const double denom = (double)w / cnt + 0.5;
    double s = 1.0 / denom;
#pragma unroll
    for (int off = 32; off > 0; off >>= 1) s += __shfl_xor(s, off);
    const double gf = 1.0 / (denom * s);
    double rw = gf * (double)w;
#pragma unroll
    for (int off = 32; off > 0; off >>= 1) rw += __shfl_xor(rw, off);
    wing[(row << 6) + lane] = (float)gf;
    if (lane == 0) rowsum[row] = rw;
}

// ---------------------------------------------------------------- banded attention (MFMA)
// Block: (b,h) x 64-row query tile, 4 waves. Numerator in single bf16 MFMA
// (error enters linearly; rowsum denominator stays exact fp64 from stats_k).
// Wave w owns i-strip [16w,16w+16): S^T = mfma(A=g-frag, B=gf-frag-in-regs)
// -> C frag (col=i=lane&15, rows=j) is written to wave-private SL rows and
// re-read as GEMM2's A-frag (no cross-wave sharing -> no barrier).
// Staging map: row sj = lane, d-block sd0 = wave*16. VT scalar transpose
// stores then span all 32 banks (2 lanes/bank = free); the R5 map
// (sj=tid>>2) had all 4 sd0 groups bank-aliased (8-way conflict).
// LDS tiles [64][72] bf16: +8 pad => b128 ops at 8-access/bank minimum.
__global__ __launch_bounds__(256)
void attn_k(const float* __restrict__ gf, const float* __restrict__ g,
            const float* __restrict__ v, const double* __restrict__ rowsum,
            unsigned short* __restrict__ aoh, unsigned short* __restrict__ aol)
{
    __shared__ unsigned short gL[64 * 72];   // [j][d] bf16
    __shared__ unsigned short VT[64 * 72];   // [d][j] bf16
    __shared__ unsigned short SL[64 * 72];   // [i][j] bf16, wave-private 16-row bands

    const int bh = blockIdx.y, it = blockIdx.x;
    const int i0 = it << 6;
    const int tid = threadIdx.x;
    const int wave = tid >> 6, lane = tid & 63;
    const int l15 = lane & 15, l4 = lane >> 4;

    // gf B-fragments: load once, keep in registers. col i = i-strip + l15,
    // k = kk*32 + l4*8.
    bf16x8 gfB[2];
    {
        const int ig = i0 + (wave << 4) + l15;
        const float* src = gf + (((size_t)(bh << 11) + ig) << 6) + (l4 << 3);
        const float4 q0 = *(const float4*)(src);
        const float4 q1 = *(const float4*)(src + 4);
        const float4 q2 = *(const float4*)(src + 32);
        const float4 q3 = *(const float4*)(src + 36);
        const us8 f0 = pack8(q0, q1), f1 = pack8(q2, q3);
        gfB[0] = (bf16x8)f0;
        gfB[1] = (bf16x8)f1;
    }

    // staging assignment: row sj = lane (0..63), d-block sd0 = wave*16
    const int sj = lane, sd0 = wave << 4;

    const int t_lo = (it >= 8) ? (it - 8) : 0;
    float4 gq[4], vq[4];
    {
        const float* gsrc = g + (((size_t)(bh << 11) + (t_lo << 6) + sj) << 6) + sd0;
        const float* vsrc = v + (((size_t)(bh << 11) + (t_lo << 6) + sj) << 6) + sd0;
#pragma unroll
        for (int q = 0; q < 4; ++q) gq[q] = *(const float4*)(gsrc + (q << 2));
#pragma unroll
        for (int q = 0; q < 4; ++q) vq[q] = *(const float4*)(vsrc + (q << 2));
    }

    f32x4 acc2[4] = {};
    const int ig_mask = i0 + (wave << 4) + l15;   // this lane's i for masking

    for (int t = t_lo; t <= it; ++t) {
        const int j0 = t << 6;
        __syncthreads();              // previous iteration's gL/VT reads done
        {   // gL[j][d0..d0+15]
            *(us8*)&gL[sj * 72 + sd0]     = pack8(gq[0], gq[1]);
            *(us8*)&gL[sj * 72 + sd0 + 8] = pack8(gq[2], gq[3]);
            // VT[d][j] transposed scalar stores (lanes span j -> 32 banks)
            const float* vf = (const float*)vq;
#pragma unroll
            for (int h = 0; h < 16; ++h)
                VT[(sd0 + h) * 72 + sj] = bf_rne(vf[h]);
        }
        __syncthreads();

        if (t < it) {                 // prefetch next tile
            const float* gsrc = g + (((size_t)(bh << 11) + j0 + 64 + sj) << 6) + sd0;
            const float* vsrc = v + (((size_t)(bh << 11) + j0 + 64 + sj) << 6) + sd0;
#pragma unroll
            for (int q = 0; q < 4; ++q) gq[q] = *(const float4*)(gsrc + (q << 2));
#pragma unroll
            for (int q = 0; q < 4; ++q) vq[q] = *(const float4*)(vsrc + (q << 2));
        }

        // GEMM1: S^T[j][i-strip] = g . gf^T
        f32x4 sfr[4] = {};
#pragma unroll
        for (int kk = 0; kk < 2; ++kk)
#pragma unroll
            for (int jm = 0; jm < 4; ++jm) {
                const bf16x8 ag = *(const bf16x8*)&gL[((jm << 4) + l15) * 72 + (kk << 5) + (l4 << 3)];
                sfr[jm] = __builtin_amdgcn_mfma_f32_16x16x32_bf16(ag, gfB[kk], sfr[jm], 0, 0, 0);
            }

        // mask + cvt -> SL (wave-private rows 16w..16w+15)
        const bool need_mask = (t == it) || (t == it - 8);
#pragma unroll
        for (int jm = 0; jm < 4; ++jm) {
            float s0 = sfr[jm][0], s1 = sfr[jm][1], s2 = sfr[jm][2], s3 = sfr[jm][3];
            if (need_mask) {
                const int jb = j0 + (jm << 4) + (l4 << 2);
                if (!(jb + 0 <= ig_mask && jb + 0 > ig_mask - WIN)) s0 = 0.f;
                if (!(jb + 1 <= ig_mask && jb + 1 > ig_mask - WIN)) s1 = 0.f;
                if (!(jb + 2 <= ig_mask && jb + 2 > ig_mask - WIN)) s2 = 0.f;
                if (!(jb + 3 <= ig_mask && jb + 3 > ig_mask - WIN)) s3 = 0.f;
            }
            us4 sl;
            sl[0] = bf_rne(s0); sl[1] = bf_rne(s1); sl[2] = bf_rne(s2); sl[3] = bf_rne(s3);
            *(us4*)&SL[((wave << 4) + l15) * 72 + (jm << 4) + (l4 << 2)] = sl;
        }

        // GEMM2: O[i-strip][d] += S . V  (A from SL, same-wave RAW; B from VT)
#pragma unroll
        for (int kk = 0; kk < 2; ++kk) {
            const bf16x8 a2 = *(const bf16x8*)&SL[((wave << 4) + l15) * 72 + (kk << 5) + (l4 << 3)];
#pragma unroll
            for (int nf = 0; nf < 4; ++nf) {
                const bf16x8 b2 = *(const bf16x8*)&VT[((nf << 4) + l15) * 72 + (kk << 5) + (l4 << 3)];
                acc2[nf] = __builtin_amdgcn_mfma_f32_16x16x32_bf16(a2, b2, acc2[nf], 0, 0, 0);
            }
        }
    }

    // epilogue: divide by fp64 rowsum, split to hi/lo bf16 planes
    const int b = bh >> 4, hh = bh & 15;
    float inv[4];
#pragma unroll
    for (int r = 0; r < 4; ++r) {
        const int ig = i0 + (wave << 4) + (l4 << 2) + r;
        double rs = rowsum[(bh << 11) + ig];
        if (!(rs > 1e-10)) rs = 1e-10;
        inv[r] = (float)(1.0 / rs);
    }
#pragma unroll
    for (int nf = 0; nf < 4; ++nf)
#pragma unroll
        for (int r = 0; r < 4; ++r) {
            const int ig = i0 + (wave << 4) + (l4 << 2) + r;
            const int d = (nf << 4) + l15;
            const float val = acc2[nf][r] * inv[r];
            unsigned short vh, vl;
            split_bf16(val, vh, vl);
            const size_t base = (((size_t)(b * NT + ig)) << 10) + (hh << 6) + d;
            aoh[base] = vh;
            aol[base] = vl;
        }
}

// ---------------------------------------------------------------- launch
// Workspace map (live ranges disjoint where overlaid):
//   gbuf  [SZ]      g        (gemm -> attn)
//   vbuf  [SZ]      v        (mgemm<1> -> attn)
//   pinb  [SZ]      prefixes (chunkscan -> winsum), then aoh/aol (attn -> mgemm<0>)
//   winb  [SZ]      xhi/xlo  (split_k -> mgemm<1>), then gene_fit (winsum -> attn)
//   wpl   [2*MW]    4 ushort W planes (tsplit -> mgemm<0>)
//   csum/cpre/rsum  dedicated tail
extern "C" void kernel_launch(void* const* d_in, const int* in_sizes, int n_in,
                              void* d_out, int out_size, void* d_ws, size_t ws_size,
                              hipStream_t stream)
{
    const float* x  = (const float*)d_in[0];
    const float* Wg = (const float*)d_in[1];
    const float* bg = (const float*)d_in[2];
    const float* Wv = (const float*)d_in[3];
    const float* bv = (const float*)d_in[4];
    const float* Wo = (const float*)d_in[5];
    const float* bo = (const float*)d_in[6];
    float* out = (float*)d_out;

    const size_t SZ = (size_t)NB * NH * NT * HD;   // 4M floats
    const size_t MW = (size_t)ND * ND;             // 1M
    const size_t CS = (size_t)NBH * NCH * HD;      // 64K

    float* gbuf = (float*)d_ws;
    float* vbuf = gbuf + SZ;
    float* pinb = vbuf + SZ;
    float* winb = pinb + SZ;
    float* wpl  = winb + SZ;
    float* csum = wpl + 2 * MW;
    float* cpre = csum + CS;
    double* rsum = (double*)(cpre + CS);

    unsigned short* xhi  = (unsigned short*)winb;
    unsigned short* xlo  = xhi + SZ;
    unsigned short* wvTh = (unsigned short*)wpl;
    unsigned short* wvTl = wvTh + MW;
    unsigned short* woTh = wvTl + MW;
    unsigned short* woTl = woTh + MW;
    unsigned short* aoh  = (unsigned short*)pinb;
    unsigned short* aol  = aoh + SZ;

    const int M = NB * NT;   // 4096

    gemm_k<<<dim3(ND >> 6, M >> 6), 256, 0, stream>>>(x, Wg, bg, gbuf, M, ND, ND);
    split_k<<<(int)(SZ / 4 / 256), 256, 0, stream>>>(x, xhi, xlo);
    tsplit_k<<<dim3(ND >> 6, ND >> 6), 256, 0, stream>>>(Wv, wvTh, wvTl);
    tsplit_k<<<dim3(ND >> 6, ND >> 6), 256, 0, stream>>>(Wo, woTh, woTl);
    mgemm_k<1><<<dim3(ND >> 7, M >> 7), 256, 0, stream>>>(xhi, xlo, wvTh, wvTl, bv, vbuf, M, ND, ND);
    chunkscan_k<<<NBH * NCH, 64, 0, stream>>>(gbuf, pinb, csum);
    chunkpre_k<<<NBH, 64, 0, stream>>>(csum, cpre);
    winsum_k<<<(NBH * NT * HD / 4) / 256, 256, 0, stream>>>(pinb, cpre, winb);
    stats_k<<<(NBH * NT) / 4, 256, 0, stream>>>(winb, rsum);
    attn_k<<<dim3(NT >> 6, NBH), 256, 0, stream>>>(winb, gbuf, vbuf, rsum, aoh, aol);
    mgemm_k<0><<<dim3(ND >> 7, M >> 7), 256, 0, stream>>>(aoh, aol, woTh, woTl, bo, out, M, ND, ND);
}

// Round 9
// 340.687 us; speedup vs baseline: 1.8469x; 1.1410x over previous
//
#include <hip/hip_runtime.h>

#define NB 2
#define NT 2048
#define ND 1024
#define NH 16
#define HD 64
#define WIN 512
#define NBH (NB*NH)      // 32
#define NCH (NT/64)      // 32 chunks of 64 along T

typedef short    bf16x8 __attribute__((ext_vector_type(8)));
typedef unsigned short us8 __attribute__((ext_vector_type(8)));
typedef unsigned short us4 __attribute__((ext_vector_type(4)));
typedef float    f32x4  __attribute__((ext_vector_type(4)));

// ---------------------------------------------------------------- helpers
// truncation split (hi/lo) -- used for Wv/Wo planes and aout planes
__device__ __forceinline__ void split_bf16(float f, unsigned short& h, unsigned short& l)
{
    unsigned u = __float_as_uint(f);
    h = (unsigned short)(u >> 16);
    float fh = __uint_as_float(u & 0xffff0000u);
    l = (unsigned short)(__float_as_uint(f - fh) >> 16);
}

// fp32 -> bf16 round-to-nearest-even
__device__ __forceinline__ unsigned short bf_rne(float f)
{
    unsigned u = __float_as_uint(f);
    u += 0x7fffu + ((u >> 16) & 1u);
    return (unsigned short)(u >> 16);
}

// RNE 3-way split: f ~= h + m + l to ~2^-33 rel (fp32-equivalent)
__device__ __forceinline__ void split3(float f, unsigned short& h,
                                       unsigned short& m, unsigned short& l)
{
    h = bf_rne(f);
    const float fh = __uint_as_float((unsigned)h << 16);
    const float r1 = f - fh;
    m = bf_rne(r1);
    const float fm = __uint_as_float((unsigned)m << 16);
    const float r2 = r1 - fm;
    l = bf_rne(r2);
}

__device__ __forceinline__ us8 pack8(float4 a, float4 b)
{
    us8 r;
    r[0] = bf_rne(a.x); r[1] = bf_rne(a.y); r[2] = bf_rne(a.z); r[3] = bf_rne(a.w);
    r[4] = bf_rne(b.x); r[5] = bf_rne(b.y); r[6] = bf_rne(b.z); r[7] = bf_rne(b.w);
    return r;
}

// ---------------------------------------------------------------- bf16x3 MFMA GEMM (g-path)
// g = x@Wg+bg at fp32-equivalent accuracy: A,B pre-split into RNE h/m/l bf16
// planes; 6 passes keep all products >= 2^-16 (hh, hm, mh, hl, lh, mm);
// dropped terms ~2^-24 rel. g perturbation stays at the validated ~1e-6
// scale (the 1e-10-clamped rowsum path tolerates this; bf16x2's 2^-17
// would be 50x larger -> knife-edge clamp-flip risk).
// Tile 128x128x32, 4 waves, same LDS swizzle as mgemm_k.
__global__ __launch_bounds__(256)
void mgemm3_k(const unsigned short* __restrict__ Ah, const unsigned short* __restrict__ Am,
              const unsigned short* __restrict__ Al,
              const unsigned short* __restrict__ Bh, const unsigned short* __restrict__ Bm,
              const unsigned short* __restrict__ Bl,
              const float* __restrict__ bias, float* __restrict__ C,
              int M, int N, int K)
{
    __shared__ unsigned short As[3][128 * 32];
    __shared__ unsigned short Bs[3][128 * 32];
    const int tid = threadIdx.x;
    const int wave = tid >> 6, lane = tid & 63;
    const int wm = wave >> 1, wn = wave & 1;
    const int m0 = blockIdx.y << 7, n0 = blockIdx.x << 7;
    const int l15 = lane & 15;

    const int srow = tid >> 1, skh = tid & 1;
    const int ssw = (srow & 3) ^ ((srow >> 2) & 3);
    const int sA0 = srow * 32 + ((((skh << 1) | 0) ^ ssw) << 3);
    const int sA1 = srow * 32 + ((((skh << 1) | 1) ^ ssw) << 3);
    const size_t aoff = (size_t)(m0 + srow) * K + (skh << 4);
    const size_t boff = (size_t)(n0 + srow) * K + (skh << 4);

    us8 a0[2], a1[2], a2[2], b0[2], b1[2], b2[2];
    a0[0] = *(const us8*)(Ah + aoff); a0[1] = *(const us8*)(Ah + aoff + 8);
    a1[0] = *(const us8*)(Am + aoff); a1[1] = *(const us8*)(Am + aoff + 8);
    a2[0] = *(const us8*)(Al + aoff); a2[1] = *(const us8*)(Al + aoff + 8);
    b0[0] = *(const us8*)(Bh + boff); b0[1] = *(const us8*)(Bh + boff + 8);
    b1[0] = *(const us8*)(Bm + boff); b1[1] = *(const us8*)(Bm + boff + 8);
    b2[0] = *(const us8*)(Bl + boff); b2[1] = *(const us8*)(Bl + boff + 8);

    const int fsw = ((lane >> 4) ^ (lane & 3) ^ ((lane & 12) >> 2)) << 3;

    f32x4 acc[4][4] = {};
    for (int k0 = 0; k0 < K; k0 += 32) {
        __syncthreads();
        *(us8*)&As[0][sA0] = a0[0]; *(us8*)&As[0][sA1] = a0[1];
        *(us8*)&As[1][sA0] = a1[0]; *(us8*)&As[1][sA1] = a1[1];
        *(us8*)&As[2][sA0] = a2[0]; *(us8*)&As[2][sA1] = a2[1];
        *(us8*)&Bs[0][sA0] = b0[0]; *(us8*)&Bs[0][sA1] = b0[1];
        *(us8*)&Bs[1][sA0] = b1[0]; *(us8*)&Bs[1][sA1] = b1[1];
        *(us8*)&Bs[2][sA0] = b2[0]; *(us8*)&Bs[2][sA1] = b2[1];
        __syncthreads();
        if (k0 + 32 < K) {
            const size_t ka = aoff + k0 + 32, kb = boff + k0 + 32;
            a0[0] = *(const us8*)(Ah + ka); a0[1] = *(const us8*)(Ah + ka + 8);
            a1[0] = *(const us8*)(Am + ka); a1[1] = *(const us8*)(Am + ka + 8);
            a2[0] = *(const us8*)(Al + ka); a2[1] = *(const us8*)(Al + ka + 8);
            b0[0] = *(const us8*)(Bh + kb); b0[1] = *(const us8*)(Bh + kb + 8);
            b1[0] = *(const us8*)(Bm + kb); b1[1] = *(const us8*)(Bm + kb + 8);
            b2[0] = *(const us8*)(Bl + kb); b2[1] = *(const us8*)(Bl + kb + 8);
        }
        bf16x8 aF[3][4], bF[3][4];
#pragma unroll
        for (int s = 0; s < 4; ++s) {
            const int ra = (wm << 6) + (s << 4) + l15;
            const int rb = (wn << 6) + (s << 4) + l15;
#pragma unroll
            for (int p = 0; p < 3; ++p) {
                aF[p][s] = *(const bf16x8*)&As[p][ra * 32 + fsw];
                bF[p][s] = *(const bf16x8*)&Bs[p][rb * 32 + fsw];
            }
        }
#pragma unroll
        for (int ms = 0; ms < 4; ++ms)
#pragma unroll
            for (int ns = 0; ns < 4; ++ns) {
                f32x4 t = acc[ms][ns];
                t = __builtin_amdgcn_mfma_f32_16x16x32_bf16(aF[0][ms], bF[0][ns], t, 0, 0, 0);
                t = __builtin_amdgcn_mfma_f32_16x16x32_bf16(aF[0][ms], bF[1][ns], t, 0, 0, 0);
                t = __builtin_amdgcn_mfma_f32_16x16x32_bf16(aF[1][ms], bF[0][ns], t, 0, 0, 0);
                t = __builtin_amdgcn_mfma_f32_16x16x32_bf16(aF[0][ms], bF[2][ns], t, 0, 0, 0);
                t = __builtin_amdgcn_mfma_f32_16x16x32_bf16(aF[2][ms], bF[0][ns], t, 0, 0, 0);
                t = __builtin_amdgcn_mfma_f32_16x16x32_bf16(aF[1][ms], bF[1][ns], t, 0, 0, 0);
                acc[ms][ns] = t;
            }
    }

    // epilogue: scatter to (B,H,T,HD); C frag col=lane&15, row=(lane>>4)*4+r
#pragma unroll
    for (int ms = 0; ms < 4; ++ms)
#pragma unroll
        for (int ns = 0; ns < 4; ++ns) {
            const int col = n0 + (wn << 6) + (ns << 4) + l15;
            const float bb = bias[col];
            const int h = col >> 6, d = col & 63;
#pragma unroll
            for (int r = 0; r < 4; ++r) {
                const int row = m0 + (wm << 6) + (ms << 4) + ((lane >> 4) << 2) + r;
                const int b = row >> 11, i = row & (NT - 1);
                C[((((size_t)(b * NH + h)) << 11) + i) * HD + d] = acc[ms][ns][r] + bb;
            }
        }
}

// ---------------------------------------------------------------- bf16x2 MFMA GEMM
template<int MODE>  // 0: row-major out; 1: scatter to (B,H,T,HD)
__global__ __launch_bounds__(256)
void mgemm_k(const unsigned short* __restrict__ Ahi, const unsigned short* __restrict__ Alo,
             const unsigned short* __restrict__ Bhi, const unsigned short* __restrict__ Blo,
             const float* __restrict__ bias, float* __restrict__ C,
             int M, int N, int K)
{
    __shared__ unsigned short As[2][128 * 32];
    __shared__ unsigned short Bs[2][128 * 32];
    const int tid = threadIdx.x;
    const int wave = tid >> 6, lane = tid & 63;
    const int wm = wave >> 1, wn = wave & 1;
    const int m0 = blockIdx.y << 7, n0 = blockIdx.x << 7;

    const int srow = tid >> 1, skh = tid & 1;
    const int ssw = (srow & 3) ^ ((srow >> 2) & 3);
    const int sA0 = srow * 32 + ((((skh << 1) | 0) ^ ssw) << 3);
    const int sA1 = srow * 32 + ((((skh << 1) | 1) ^ ssw) << 3);
    const size_t aoff = (size_t)(m0 + srow) * K + (skh << 4);
    const size_t boff = (size_t)(n0 + srow) * K + (skh << 4);

    us8 ah0 = *(const us8*)(Ahi + aoff), ah1 = *(const us8*)(Ahi + aoff + 8);
    us8 al0 = *(const us8*)(Alo + aoff), al1 = *(const us8*)(Alo + aoff + 8);
    us8 bh0 = *(const us8*)(Bhi + boff), bh1 = *(const us8*)(Bhi + boff + 8);
    us8 bl0 = *(const us8*)(Blo + boff), bl1 = *(const us8*)(Blo + boff + 8);

    const int fsw = ((lane >> 4) ^ (lane & 3) ^ ((lane & 12) >> 2)) << 3;

    f32x4 acc[4][4] = {};
    for (int k0 = 0; k0 < K; k0 += 32) {
        __syncthreads();
        *(us8*)&As[0][sA0] = ah0; *(us8*)&As[0][sA1] = ah1;
        *(us8*)&As[1][sA0] = al0; *(us8*)&As[1][sA1] = al1;
        *(us8*)&Bs[0][sA0] = bh0; *(us8*)&Bs[0][sA1] = bh1;
        *(us8*)&Bs[1][sA0] = bl0; *(us8*)&Bs[1][sA1] = bl1;
        __syncthreads();
        if (k0 + 32 < K) {
            const size_t ka = aoff + k0 + 32, kb = boff + k0 + 32;
            ah0 = *(const us8*)(Ahi + ka); ah1 = *(const us8*)(Ahi + ka + 8);
            al0 = *(const us8*)(Alo + ka); al1 = *(const us8*)(Alo + ka + 8);
            bh0 = *(const us8*)(Bhi + kb); bh1 = *(const us8*)(Bhi + kb + 8);
            bl0 = *(const us8*)(Blo + kb); bl1 = *(const us8*)(Blo + kb + 8);
        }
        bf16x8 aH[4], aL[4], bH[4], bL[4];
#pragma unroll
        for (int s = 0; s < 4; ++s) {
            const int ra = (wm << 6) + (s << 4) + (lane & 15);
            const int rb = (wn << 6) + (s << 4) + (lane & 15);
            aH[s] = *(const bf16x8*)&As[0][ra * 32 + fsw];
            aL[s] = *(const bf16x8*)&As[1][ra * 32 + fsw];
            bH[s] = *(const bf16x8*)&Bs[0][rb * 32 + fsw];
            bL[s] = *(const bf16x8*)&Bs[1][rb * 32 + fsw];
        }
#pragma unroll
        for (int ms = 0; ms < 4; ++ms)
#pragma unroll
            for (int ns = 0; ns < 4; ++ns) {
                acc[ms][ns] = __builtin_amdgcn_mfma_f32_16x16x32_bf16(aH[ms], bH[ns], acc[ms][ns], 0, 0, 0);
                acc[ms][ns] = __builtin_amdgcn_mfma_f32_16x16x32_bf16(aH[ms], bL[ns], acc[ms][ns], 0, 0, 0);
                acc[ms][ns] = __builtin_amdgcn_mfma_f32_16x16x32_bf16(aL[ms], bH[ns], acc[ms][ns], 0, 0, 0);
            }
    }

#pragma unroll
    for (int ms = 0; ms < 4; ++ms)
#pragma unroll
        for (int ns = 0; ns < 4; ++ns) {
            const int col = n0 + (wn << 6) + (ns << 4) + (lane & 15);
            const float bb = bias[col];
#pragma unroll
            for (int r = 0; r < 4; ++r) {
                const int row = m0 + (wm << 6) + (ms << 4) + ((lane >> 4) << 2) + r;
                const float val = acc[ms][ns][r] + bb;
                if (MODE == 0) {
                    C[(size_t)row * N + col] = val;
                } else {
                    const int b = row >> 11, i = row & (NT - 1);
                    const int h = col >> 6;
                    C[((((size_t)(b * NH + h)) << 11) + i) * HD + (col & 63)] = val;
                }
            }
        }
}

// ---------------------------------------------------------------- prep kernels
// x -> RNE h/m/l planes. (h,m) double as the v-GEMM's bf16x2 operand pair
// (RNE h+m is strictly more accurate than the old truncation hi/lo).
__global__ __launch_bounds__(256)
void split3_k(const float* __restrict__ x, unsigned short* __restrict__ xh,
              unsigned short* __restrict__ xm, unsigned short* __restrict__ xl)
{
    const int e0 = (blockIdx.x * 256 + threadIdx.x) << 2;
    const float4 v = *(const float4*)&x[e0];
    ushort4 hh, mm, ll;
    split3(v.x, hh.x, mm.x, ll.x); split3(v.y, hh.y, mm.y, ll.y);
    split3(v.z, hh.z, mm.z, ll.z); split3(v.w, hh.w, mm.w, ll.w);
    *(ushort4*)&xh[e0] = hh;
    *(ushort4*)&xm[e0] = mm;
    *(ushort4*)&xl[e0] = ll;
}

// W [k][n] fp32 -> WT [n][k] truncation hi/lo planes (Wv, Wo).
__global__ __launch_bounds__(256)
void tsplit_k(const float* __restrict__ W, unsigned short* __restrict__ Th,
              unsigned short* __restrict__ Tl)
{
    __shared__ float Ls[64][68];   // 272B stride: float4 ops stay 16B-aligned
    const int n0 = blockIdx.x << 6, k0 = blockIdx.y << 6;
    const int tid = threadIdx.x;
    const int r16 = tid >> 4, c4 = (tid & 15) << 2;
#pragma unroll
    for (int j = 0; j < 4; ++j) {
        const int row = r16 + (j << 4);
        *(float4*)&Ls[row][c4] = *(const float4*)&W[(size_t)(k0 + row) * ND + n0 + c4];
    }
    __syncthreads();
#pragma unroll
    for (int j = 0; j < 4; ++j) {
        const int n = r16 + (j << 4);
        ushort4 hh, ll;
        split_bf16(Ls[c4 + 0][n], hh.x, ll.x);
        split_bf16(Ls[c4 + 1][n], hh.y, ll.y);
        split_bf16(Ls[c4 + 2][n], hh.z, ll.z);
        split_bf16(Ls[c4 + 3][n], hh.w, ll.w);
        const size_t o = (size_t)(n0 + n) * ND + k0 + c4;
        *(ushort4*)&Th[o] = hh;
        *(ushort4*)&Tl[o] = ll;
    }
}

// Wg [k][n] fp32 -> WT [n][k] RNE h/m/l planes.
__global__ __launch_bounds__(256)
void tsplit3_k(const float* __restrict__ W, unsigned short* __restrict__ T0,
               unsigned short* __restrict__ T1, unsigned short* __restrict__ T2)
{
    __shared__ float Ls[64][68];
    const int n0 = blockIdx.x << 6, k0 = blockIdx.y << 6;
    const int tid = threadIdx.x;
    const int r16 = tid >> 4, c4 = (tid & 15) << 2;
#pragma unroll
    for (int j = 0; j < 4; ++j) {
        const int row = r16 + (j << 4);
        *(float4*)&Ls[row][c4] = *(const float4*)&W[(size_t)(k0 + row) * ND + n0 + c4];
    }
    __syncthreads();
#pragma unroll
    for (int j = 0; j < 4; ++j) {
        const int n = r16 + (j << 4);
        ushort4 hh, mm, ll;
        split3(Ls[c4 + 0][n], hh.x, mm.x, ll.x);
        split3(Ls[c4 + 1][n], hh.y, mm.y, ll.y);
        split3(Ls[c4 + 2][n], hh.z, mm.z, ll.z);
        split3(Ls[c4 + 3][n], hh.w, mm.w, ll.w);
        const size_t o = (size_t)(n0 + n) * ND + k0 + c4;
        *(ushort4*)&T0[o] = hh;
        *(ushort4*)&T1[o] = mm;
        *(ushort4*)&T2[o] = ll;
    }
}

// ---------------------------------------------------------------- windowed-sum machinery
__global__ __launch_bounds__(64)
void chunkscan_k(const float* __restrict__ g, float* __restrict__ Pin,
                 float* __restrict__ Csum)
{
    const int blk = blockIdx.x;
    const int lane = threadIdx.x;
    const int base = (blk << 12) + lane;
    float run = 0.f;
#pragma unroll 16
    for (int t = 0; t < 64; ++t) {
        run += g[base + (t << 6)];
        Pin[base + (t << 6)] = run;
    }
    Csum[(blk << 6) + lane] = run;
}

__global__ __launch_bounds__(64)
void chunkpre_k(const float* __restrict__ Csum, float* __restrict__ Cpre)
{
    const int bh = blockIdx.x, lane = threadIdx.x;
    float run = 0.f;
    for (int c = 0; c < NCH; ++c) {
        run += Csum[((bh * NCH + c) << 6) + lane];
        Cpre[((bh * NCH + c) << 6) + lane] = run;
    }
}

__global__ __launch_bounds__(256)
void winsum_k(const float* __restrict__ Pin, const float* __restrict__ Cpre,
              float* __restrict__ wout)
{
    const int idx = blockIdx.x * 256 + threadIdx.x;
    const int e0 = idx << 2;
    const int row = e0 >> 6;
    const int d = e0 & 63;
    const int bh = row >> 11;
    const int i = row & (NT - 1);
    const int c = i >> 6;

    float4 p = *(const float4*)&Pin[e0];
    float ax = p.x, ay = p.y, az = p.z, aw = p.w;
    if (c > 0) {
        const float4 q = *(const float4*)&Cpre[((bh * NCH + c - 1) << 6) + d];
        ax += q.x; ay += q.y; az += q.z; aw += q.w;
    }
    if (i >= WIN) {
        const int i2 = i - WIN;
        const int c2 = i2 >> 6;
        const float4 p2 = *(const float4*)&Pin[(((bh << 11) + i2) << 6) + d];
        ax -= p2.x; ay -= p2.y; az -= p2.z; aw -= p2.w;
        if (c2 > 0) {
            const float4 q2 = *(const float4*)&Cpre[((bh * NCH + c2 - 1) << 6) + d];
            ax -= q2.x; ay -= q2.y; az -= q2.z; aw -= q2.w;
        }
    }
    *(float4*)&wout[e0] = make_float4(ax, ay, az, aw);
}

__global__ __launch_bounds__(256)
void stats_k(float* __restrict__ wing, double* __restrict__ rowsum)
{
    const int row = (blockIdx.x << 2) + (threadIdx.x >> 6);
    const int lane = threadIdx.x & 63;
    const int i = row & (NT - 1);
    const float w = wing[(row << 6) + lane];
    const double cnt = (double)((i + 1 < WIN) ? (i + 1) : WIN);
    const double denom = (double)w / cnt + 0.5;
    double s = 1.0 / denom;
#pragma unroll
    for (int off = 32; off > 0; off >>= 1) s += __shfl_xor(s, off);
    const double gf = 1.0 / (denom * s);
    double rw = gf * (double)w;
#pragma unroll
    for (int off = 32; off > 0; off >>= 1) rw += __shfl_xor(rw, off);
    wing[(row << 6) + lane] = (float)gf;
    if (lane == 0) rowsum[row] = rw;
}

// ---------------------------------------------------------------- banded attention (MFMA)
__global__ __launch_bounds__(256)
void attn_k(const float* __restrict__ gf, const float* __restrict__ g,
            const float* __restrict__ v, const double* __restrict__ rowsum,
            unsigned short* __restrict__ aoh, unsigned short* __restrict__ aol)
{
    __shared__ unsigned short gL[64 * 72];   // [j][d] bf16
    __shared__ unsigned short VT[64 * 72];   // [d][j] bf16
    __shared__ unsigned short SL[64 * 72];   // [i][j] bf16, wave-private 16-row bands

    const int bh = blockIdx.y, it = blockIdx.x;
    const int i0 = it << 6;
    const int tid = threadIdx.x;
    const int wave = tid >> 6, lane = tid & 63;
    const int l15 = lane & 15, l4 = lane >> 4;

    bf16x8 gfB[2];
    {
        const int ig = i0 + (wave << 4) + l15;
        const float* src = gf + (((size_t)(bh << 11) + ig) << 6) + (l4 << 3);
        const float4 q0 = *(const float4*)(src);
        const float4 q1 = *(const float4*)(src + 4);
        const float4 q2 = *(const float4*)(src + 32);
        const float4 q3 = *(const float4*)(src + 36);
        const us8 f0 = pack8(q0, q1), f1 = pack8(q2, q3);
        gfB[0] = (bf16x8)f0;
        gfB[1] = (bf16x8)f1;
    }

    const int sj = lane, sd0 = wave << 4;

    const int t_lo = (it >= 8) ? (it - 8) : 0;
    float4 gq[4], vq[4];
    {
        const float* gsrc = g + (((size_t)(bh << 11) + (t_lo << 6) + sj) << 6) + sd0;
        const float* vsrc = v + (((size_t)(bh << 11) + (t_lo << 6) + sj) << 6) + sd0;
#pragma unroll
        for (int q = 0; q < 4; ++q) gq[q] = *(const float4*)(gsrc + (q << 2));
#pragma unroll
        for (int q = 0; q < 4; ++q) vq[q] = *(const float4*)(vsrc + (q << 2));
    }

    f32x4 acc2[4] = {};
    const int ig_mask = i0 + (wave << 4) + l15;

    for (int t = t_lo; t <= it; ++t) {
        const int j0 = t << 6;
        __syncthreads();
        {
            *(us8*)&gL[sj * 72 + sd0]     = pack8(gq[0], gq[1]);
            *(us8*)&gL[sj * 72 + sd0 + 8] = pack8(gq[2], gq[3]);
            const float* vf = (const float*)vq;
#pragma unroll
            for (int h = 0; h < 16; ++h)
                VT[(sd0 + h) * 72 + sj] = bf_rne(vf[h]);
        }
        __syncthreads();

        if (t < it) {
            const float* gsrc = g + (((size_t)(bh << 11) + j0 + 64 + sj) << 6) + sd0;
            const float* vsrc = v + (((size_t)(bh << 11) + j0 + 64 + sj) << 6) + sd0;
#pragma unroll
            for (int q = 0; q < 4; ++q) gq[q] = *(const float4*)(gsrc + (q << 2));
#pragma unroll
            for (int q = 0; q < 4; ++q) vq[q] = *(const float4*)(vsrc + (q << 2));
        }

        f32x4 sfr[4] = {};
#pragma unroll
        for (int kk = 0; kk < 2; ++kk)
#pragma unroll
            for (int jm = 0; jm < 4; ++jm) {
                const bf16x8 ag = *(const bf16x8*)&gL[((jm << 4) + l15) * 72 + (kk << 5) + (l4 << 3)];
                sfr[jm] = __builtin_amdgcn_mfma_f32_16x16x32_bf16(ag, gfB[kk], sfr[jm], 0, 0, 0);
            }

        const bool need_mask = (t == it) || (t == it - 8);
#pragma unroll
        for (int jm = 0; jm < 4; ++jm) {
            float s0 = sfr[jm][0], s1 = sfr[jm][1], s2 = sfr[jm][2], s3 = sfr[jm][3];
            if (need_mask) {
                const int jb = j0 + (jm << 4) + (l4 << 2);
                if (!(jb + 0 <= ig_mask && jb + 0 > ig_mask - WIN)) s0 = 0.f;
                if (!(jb + 1 <= ig_mask && jb + 1 > ig_mask - WIN)) s1 = 0.f;
                if (!(jb + 2 <= ig_mask && jb + 2 > ig_mask - WIN)) s2 = 0.f;
                if (!(jb + 3 <= ig_mask && jb + 3 > ig_mask - WIN)) s3 = 0.f;
            }
            us4 sl;
            sl[0] = bf_rne(s0); sl[1] = bf_rne(s1); sl[2] = bf_rne(s2); sl[3] = bf_rne(s3);
            *(us4*)&SL[((wave << 4) + l15) * 72 + (jm << 4) + (l4 << 2)] = sl;
        }

#pragma unroll
        for (int kk = 0; kk < 2; ++kk) {
            const bf16x8 a2 = *(const bf16x8*)&SL[((wave << 4) + l15) * 72 + (kk << 5) + (l4 << 3)];
#pragma unroll
            for (int nf = 0; nf < 4; ++nf) {
                const bf16x8 b2 = *(const bf16x8*)&VT[((nf << 4) + l15) * 72 + (kk << 5) + (l4 << 3)];
                acc2[nf] = __builtin_amdgcn_mfma_f32_16x16x32_bf16(a2, b2, acc2[nf], 0, 0, 0);
            }
        }
    }

    const int b = bh >> 4, hh = bh & 15;
    float inv[4];
#pragma unroll
    for (int r = 0; r < 4; ++r) {
        const int ig = i0 + (wave << 4) + (l4 << 2) + r;
        double rs = rowsum[(bh << 11) + ig];
        if (!(rs > 1e-10)) rs = 1e-10;
        inv[r] = (float)(1.0 / rs);
    }
#pragma unroll
    for (int nf = 0; nf < 4; ++nf)
#pragma unroll
        for (int r = 0; r < 4; ++r) {
            const int ig = i0 + (wave << 4) + (l4 << 2) + r;
            const int d = (nf << 4) + l15;
            const float val = acc2[nf][r] * inv[r];
            unsigned short vh, vl;
            split_bf16(val, vh, vl);
            const size_t base = (((size_t)(b * NT + ig)) << 10) + (hh << 6) + d;
            aoh[base] = vh;
            aol[base] = vl;
        }
}

// ---------------------------------------------------------------- launch
// Workspace map (~78 MB; overlays have disjoint live ranges):
//   gbuf [SZ]    g          (mgemm3 -> attn)
//   vbuf [SZ]    v          (mgemm<1> -> attn)
//   pinb [SZ]    xl (split3 -> mgemm3/mgemm<1>), then prefixes (chunkscan ->
//                winsum), then aoh/aol (attn -> mgemm<0>)
//   winb [SZ]    xh+xm (split3 -> mgemm<1>), then gene_fit (winsum -> attn)
//   wpl  [7*MW us] wvT h/l, woT h/l, wgT 0/1/2 (tsplit -> mgemms)
//   csum/cpre/rsum overlay wgT planes (dead after mgemm3; born at chunkscan)
extern "C" void kernel_launch(void* const* d_in, const int* in_sizes, int n_in,
                              void* d_out, int out_size, void* d_ws, size_t ws_size,
                              hipStream_t stream)
{
    const float* x  = (const float*)d_in[0];
    const float* Wg = (const float*)d_in[1];
    const float* bg = (const float*)d_in[2];
    const float* Wv = (const float*)d_in[3];
    const float* bv = (const float*)d_in[4];
    const float* Wo = (const float*)d_in[5];
    const float* bo = (const float*)d_in[6];
    float* out = (float*)d_out;

    const size_t SZ = (size_t)NB * NH * NT * HD;   // 4M floats
    const size_t MW = (size_t)ND * ND;             // 1M
    const size_t CS = (size_t)NBH * NCH * HD;      // 64K

    float* gbuf = (float*)d_ws;
    float* vbuf = gbuf + SZ;
    float* pinb = vbuf + SZ;
    float* winb = pinb + SZ;
    float* wpl  = winb + SZ;

    unsigned short* wvTh = (unsigned short*)wpl;
    unsigned short* wvTl = wvTh + MW;
    unsigned short* woTh = wvTl + MW;
    unsigned short* woTl = woTh + MW;
    unsigned short* wgT0 = woTl + MW;
    unsigned short* wgT1 = wgT0 + MW;
    unsigned short* wgT2 = wgT1 + MW;

    float* csum = (float*)wgT0;            // overlay: wgT dead after mgemm3
    float* cpre = csum + CS;
    double* rsum = (double*)(cpre + CS);

    unsigned short* xh  = (unsigned short*)winb;
    unsigned short* xm  = xh + SZ;
    unsigned short* xl  = (unsigned short*)pinb;   // dead before chunkscan writes pinb
    unsigned short* aoh = (unsigned short*)pinb;
    unsigned short* aol = aoh + SZ;

    const int M = NB * NT;   // 4096

    split3_k<<<(int)(SZ / 4 / 256), 256, 0, stream>>>(x, xh, xm, xl);
    tsplit3_k<<<dim3(ND >> 6, ND >> 6), 256, 0, stream>>>(Wg, wgT0, wgT1, wgT2);
    tsplit_k<<<dim3(ND >> 6, ND >> 6), 256, 0, stream>>>(Wv, wvTh, wvTl);
    tsplit_k<<<dim3(ND >> 6, ND >> 6), 256, 0, stream>>>(Wo, woTh, woTl);
    mgemm3_k<<<dim3(ND >> 7, M >> 7), 256, 0, stream>>>(xh, xm, xl, wgT0, wgT1, wgT2, bg, gbuf, M, ND, ND);
    mgemm_k<1><<<dim3(ND >> 7, M >> 7), 256, 0, stream>>>(xh, xm, wvTh, wvTl, bv, vbuf, M, ND, ND);
    chunkscan_k<<<NBH * NCH, 64, 0, stream>>>(gbuf, pinb, csum);
    chunkpre_k<<<NBH, 64, 0, stream>>>(csum, cpre);
    winsum_k<<<(NBH * NT * HD / 4) / 256, 256, 0, stream>>>(pinb, cpre, winb);
    stats_k<<<(NBH * NT) / 4, 256, 0, stream>>>(winb, rsum);
    attn_k<<<dim3(NT >> 6, NBH), 256, 0, stream>>>(winb, gbuf, vbuf, rsum, aoh, aol);
    mgemm_k<0><<<dim3(ND >> 7, M >> 7), 256, 0, stream>>>(aoh, aol, woTh, woTl, bo, out, M, ND, ND);
}

// Round 11
// 333.720 us; speedup vs baseline: 1.8854x; 1.0209x over previous
//
#include <hip/hip_runtime.h>

#define NB 2
#define NT 2048
#define ND 1024
#define NH 16
#define HD 64
#define WIN 512
#define NBH (NB*NH)      // 32
#define NCH (NT/64)      // 32 chunks of 64 along T

typedef short    bf16x8 __attribute__((ext_vector_type(8)));
typedef unsigned short us8 __attribute__((ext_vector_type(8)));
typedef unsigned short us4 __attribute__((ext_vector_type(4)));
typedef float    f32x4  __attribute__((ext_vector_type(4)));

// ---------------------------------------------------------------- helpers
__device__ __forceinline__ void split_bf16(float f, unsigned short& h, unsigned short& l)
{
    unsigned u = __float_as_uint(f);
    h = (unsigned short)(u >> 16);
    float fh = __uint_as_float(u & 0xffff0000u);
    l = (unsigned short)(__float_as_uint(f - fh) >> 16);
}

__device__ __forceinline__ unsigned short bf_rne(float f)
{
    unsigned u = __float_as_uint(f);
    u += 0x7fffu + ((u >> 16) & 1u);
    return (unsigned short)(u >> 16);
}

// RNE 3-way split: f ~= h + m + l to ~2^-33 rel (fp32-equivalent)
__device__ __forceinline__ void split3(float f, unsigned short& h,
                                       unsigned short& m, unsigned short& l)
{
    h = bf_rne(f);
    const float fh = __uint_as_float((unsigned)h << 16);
    const float r1 = f - fh;
    m = bf_rne(r1);
    const float fm = __uint_as_float((unsigned)m << 16);
    const float r2 = r1 - fm;
    l = bf_rne(r2);
}

__device__ __forceinline__ us8 pack8(float4 a, float4 b)
{
    us8 r;
    r[0] = bf_rne(a.x); r[1] = bf_rne(a.y); r[2] = bf_rne(a.z); r[3] = bf_rne(a.w);
    r[4] = bf_rne(b.x); r[5] = bf_rne(b.y); r[6] = bf_rne(b.z); r[7] = bf_rne(b.w);
    return r;
}

// XCD-rectangle swizzle for an 8(x) x 32(y) grid of 128x128 tiles:
// hardware slot s -> XCD c = s&7 owns the 4x8 rectangle m-rows [4c,4c+4).
// A-panels (3-4 MB) then fit the XCD-private 4 MB L2. Bijective (256 % 8 == 0).
__device__ __forceinline__ void xcd_tile(int& m0, int& n0)
{
    const int s = blockIdx.y * 8 + blockIdx.x;
    const int c = s & 7, r = s >> 3;
    m0 = ((c << 2) | (r & 3)) << 7;
    n0 = (r >> 2) << 7;
}

// ---------------------------------------------------------------- bf16x3 MFMA GEMM (g-path)
// g = x@Wg+bg at fp32-equivalent accuracy (RNE h/m/l planes, 6 passes).
// Double-buffered LDS, ONE barrier per K-step: stage-writes of tile t+1
// overlap MFMA of tile t (1 block/CU -> barrier drain was fully exposed).
#define LOADT3(koff) { const size_t ka = aoff + (koff), kb = boff + (koff);            \
    a0[0]=*(const us8*)(Ah+ka); a0[1]=*(const us8*)(Ah+ka+8);                          \
    a1[0]=*(const us8*)(Am+ka); a1[1]=*(const us8*)(Am+ka+8);                          \
    a2[0]=*(const us8*)(Al+ka); a2[1]=*(const us8*)(Al+ka+8);                          \
    b0[0]=*(const us8*)(Bh+kb); b0[1]=*(const us8*)(Bh+kb+8);                          \
    b1[0]=*(const us8*)(Bm+kb); b1[1]=*(const us8*)(Bm+kb+8);                          \
    b2[0]=*(const us8*)(Bl+kb); b2[1]=*(const us8*)(Bl+kb+8); }
#define STORET3(buf) {                                                                  \
    *(us8*)&As[buf][0][sA0]=a0[0]; *(us8*)&As[buf][0][sA1]=a0[1];                      \
    *(us8*)&As[buf][1][sA0]=a1[0]; *(us8*)&As[buf][1][sA1]=a1[1];                      \
    *(us8*)&As[buf][2][sA0]=a2[0]; *(us8*)&As[buf][2][sA1]=a2[1];                      \
    *(us8*)&Bs[buf][0][sA0]=b0[0]; *(us8*)&Bs[buf][0][sA1]=b0[1];                      \
    *(us8*)&Bs[buf][1][sA0]=b1[0]; *(us8*)&Bs[buf][1][sA1]=b1[1];                      \
    *(us8*)&Bs[buf][2][sA0]=b2[0]; *(us8*)&Bs[buf][2][sA1]=b2[1]; }

__global__ __launch_bounds__(256)
void mgemm3_k(const unsigned short* __restrict__ Ah, const unsigned short* __restrict__ Am,
              const unsigned short* __restrict__ Al,
              const unsigned short* __restrict__ Bh, const unsigned short* __restrict__ Bm,
              const unsigned short* __restrict__ Bl,
              const float* __restrict__ bias, float* __restrict__ C,
              int M, int N, int K)
{
    __shared__ unsigned short As[2][3][128 * 32];   // 48 KB
    __shared__ unsigned short Bs[2][3][128 * 32];   // 48 KB
    const int tid = threadIdx.x;
    const int wave = tid >> 6, lane = tid & 63;
    const int wm = wave >> 1, wn = wave & 1;
    int m0, n0;
    xcd_tile(m0, n0);
    const int l15 = lane & 15;

    const int srow = tid >> 1, skh = tid & 1;
    const int ssw = (srow & 3) ^ ((srow >> 2) & 3);
    const int sA0 = srow * 32 + ((((skh << 1) | 0) ^ ssw) << 3);
    const int sA1 = srow * 32 + ((((skh << 1) | 1) ^ ssw) << 3);
    const size_t aoff = (size_t)(m0 + srow) * K + (skh << 4);
    const size_t boff = (size_t)(n0 + srow) * K + (skh << 4);

    us8 a0[2], a1[2], a2[2], b0[2], b1[2], b2[2];
    LOADT3(0);
    STORET3(0);
    LOADT3(32);
    __syncthreads();

    const int fsw = ((lane >> 4) ^ (lane & 3) ^ ((lane & 12) >> 2)) << 3;

    f32x4 acc[4][4] = {};
    for (int k0 = 0; k0 < K; k0 += 32) {
        const int cur = (k0 >> 5) & 1;
        // fragment reads from buf[cur] (issued first so MFMAs start early)
        bf16x8 aF[3][4], bF[3][4];
#pragma unroll
        for (int s = 0; s < 4; ++s) {
            const int ra = (wm << 6) + (s << 4) + l15;
            const int rb = (wn << 6) + (s << 4) + l15;
#pragma unroll
            for (int p = 0; p < 3; ++p) {
                aF[p][s] = *(const bf16x8*)&As[cur][p][ra * 32 + fsw];
                bF[p][s] = *(const bf16x8*)&Bs[cur][p][rb * 32 + fsw];
            }
        }
        // stage tile k0+32 into the other buffer (overlaps MFMA below)
        if (k0 + 32 < K) STORET3(cur ^ 1);
        // prefetch tile k0+64 -> regs (hidden under MFMA)
        if (k0 + 64 < K) LOADT3(k0 + 64);
#pragma unroll
        for (int ms = 0; ms < 4; ++ms)
#pragma unroll
            for (int ns = 0; ns < 4; ++ns) {
                f32x4 t = acc[ms][ns];
                t = __builtin_amdgcn_mfma_f32_16x16x32_bf16(aF[0][ms], bF[0][ns], t, 0, 0, 0);
                t = __builtin_amdgcn_mfma_f32_16x16x32_bf16(aF[0][ms], bF[1][ns], t, 0, 0, 0);
                t = __builtin_amdgcn_mfma_f32_16x16x32_bf16(aF[1][ms], bF[0][ns], t, 0, 0, 0);
                t = __builtin_amdgcn_mfma_f32_16x16x32_bf16(aF[0][ms], bF[2][ns], t, 0, 0, 0);
                t = __builtin_amdgcn_mfma_f32_16x16x32_bf16(aF[2][ms], bF[0][ns], t, 0, 0, 0);
                t = __builtin_amdgcn_mfma_f32_16x16x32_bf16(aF[1][ms], bF[1][ns], t, 0, 0, 0);
                acc[ms][ns] = t;
            }
        __syncthreads();
    }

    // epilogue: scatter to (B,H,T,HD); C frag col=lane&15, row=(lane>>4)*4+r
#pragma unroll
    for (int ms = 0; ms < 4; ++ms)
#pragma unroll
        for (int ns = 0; ns < 4; ++ns) {
            const int col = n0 + (wn << 6) + (ns << 4) + l15;
            const float bb = bias[col];
            const int h = col >> 6, d = col & 63;
#pragma unroll
            for (int r = 0; r < 4; ++r) {
                const int row = m0 + (wm << 6) + (ms << 4) + ((lane >> 4) << 2) + r;
                const int b = row >> 11, i = row & (NT - 1);
                C[((((size_t)(b * NH + h)) << 11) + i) * HD + d] = acc[ms][ns][r] + bb;
            }
        }
}

// ---------------------------------------------------------------- bf16x2 MFMA GEMM (dbuf)
#define LOADT2(koff) { const size_t ka = aoff + (koff), kb = boff + (koff);            \
    ah0=*(const us8*)(Ahi+ka); ah1=*(const us8*)(Ahi+ka+8);                            \
    al0=*(const us8*)(Alo+ka); al1=*(const us8*)(Alo+ka+8);                            \
    bh0=*(const us8*)(Bhi+kb); bh1=*(const us8*)(Bhi+kb+8);                            \
    bl0=*(const us8*)(Blo+kb); bl1=*(const us8*)(Blo+kb+8); }
#define STORET2(buf) {                                                                  \
    *(us8*)&As[buf][0][sA0]=ah0; *(us8*)&As[buf][0][sA1]=ah1;                          \
    *(us8*)&As[buf][1][sA0]=al0; *(us8*)&As[buf][1][sA1]=al1;                          \
    *(us8*)&Bs[buf][0][sA0]=bh0; *(us8*)&Bs[buf][0][sA1]=bh1;                          \
    *(us8*)&Bs[buf][1][sA0]=bl0; *(us8*)&Bs[buf][1][sA1]=bl1; }

template<int MODE>  // 0: row-major out; 1: scatter to (B,H,T,HD)
__global__ __launch_bounds__(256)
void mgemm_k(const unsigned short* __restrict__ Ahi, const unsigned short* __restrict__ Alo,
             const unsigned short* __restrict__ Bhi, const unsigned short* __restrict__ Blo,
             const float* __restrict__ bias, float* __restrict__ C,
             int M, int N, int K)
{
    __shared__ unsigned short As[2][2][128 * 32];   // 32 KB
    __shared__ unsigned short Bs[2][2][128 * 32];   // 32 KB
    const int tid = threadIdx.x;
    const int wave = tid >> 6, lane = tid & 63;
    const int wm = wave >> 1, wn = wave & 1;
    int m0, n0;
    xcd_tile(m0, n0);
    const int l15 = lane & 15;

    const int srow = tid >> 1, skh = tid & 1;
    const int ssw = (srow & 3) ^ ((srow >> 2) & 3);
    const int sA0 = srow * 32 + ((((skh << 1) | 0) ^ ssw) << 3);
    const int sA1 = srow * 32 + ((((skh << 1) | 1) ^ ssw) << 3);
    const size_t aoff = (size_t)(m0 + srow) * K + (skh << 4);
    const size_t boff = (size_t)(n0 + srow) * K + (skh << 4);

    us8 ah0, ah1, al0, al1, bh0, bh1, bl0, bl1;
    LOADT2(0);
    STORET2(0);
    LOADT2(32);
    __syncthreads();

    const int fsw = ((lane >> 4) ^ (lane & 3) ^ ((lane & 12) >> 2)) << 3;

    f32x4 acc[4][4] = {};
    for (int k0 = 0; k0 < K; k0 += 32) {
        const int cur = (k0 >> 5) & 1;
        bf16x8 aH[4], aL[4], bH[4], bL[4];
#pragma unroll
        for (int s = 0; s < 4; ++s) {
            const int ra = (wm << 6) + (s << 4) + l15;
            const int rb = (wn << 6) + (s << 4) + l15;
            aH[s] = *(const bf16x8*)&As[cur][0][ra * 32 + fsw];
            aL[s] = *(const bf16x8*)&As[cur][1][ra * 32 + fsw];
            bH[s] = *(const bf16x8*)&Bs[cur][0][rb * 32 + fsw];
            bL[s] = *(const bf16x8*)&Bs[cur][1][rb * 32 + fsw];
        }
        if (k0 + 32 < K) STORET2(cur ^ 1);
        if (k0 + 64 < K) LOADT2(k0 + 64);
#pragma unroll
        for (int ms = 0; ms < 4; ++ms)
#pragma unroll
            for (int ns = 0; ns < 4; ++ns) {
                acc[ms][ns] = __builtin_amdgcn_mfma_f32_16x16x32_bf16(aH[ms], bH[ns], acc[ms][ns], 0, 0, 0);
                acc[ms][ns] = __builtin_amdgcn_mfma_f32_16x16x32_bf16(aH[ms], bL[ns], acc[ms][ns], 0, 0, 0);
                acc[ms][ns] = __builtin_amdgcn_mfma_f32_16x16x32_bf16(aL[ms], bH[ns], acc[ms][ns], 0, 0, 0);
            }
        __syncthreads();
    }

#pragma unroll
    for (int ms = 0; ms < 4; ++ms)
#pragma unroll
        for (int ns = 0; ns < 4; ++ns) {
            const int col = n0 + (wn << 6) + (ns << 4) + l15;
            const float bb = bias[col];
#pragma unroll
            for (int r = 0; r < 4; ++r) {
                const int row = m0 + (wm << 6) + (ms << 4) + ((lane >> 4) << 2) + r;
                const float val = acc[ms][ns][r] + bb;
                if (MODE == 0) {
                    C[(size_t)row * N + col] = val;
                } else {
                    const int b = row >> 11, i = row & (NT - 1);
                    const int h = col >> 6;
                    C[((((size_t)(b * NH + h)) << 11) + i) * HD + (col & 63)] = val;
                }
            }
        }
}

// ---------------------------------------------------------------- prep kernels
__global__ __launch_bounds__(256)
void split3_k(const float* __restrict__ x, unsigned short* __restrict__ xh,
              unsigned short* __restrict__ xm, unsigned short* __restrict__ xl)
{
    const int e0 = (blockIdx.x * 256 + threadIdx.x) << 2;
    const float4 v = *(const float4*)&x[e0];
    ushort4 hh, mm, ll;
    split3(v.x, hh.x, mm.x, ll.x); split3(v.y, hh.y, mm.y, ll.y);
    split3(v.z, hh.z, mm.z, ll.z); split3(v.w, hh.w, mm.w, ll.w);
    *(ushort4*)&xh[e0] = hh;
    *(ushort4*)&xm[e0] = mm;
    *(ushort4*)&xl[e0] = ll;
}

// W [k][n] fp32 -> WT [n][k] truncation hi/lo planes (Wv, Wo).
__global__ __launch_bounds__(256)
void tsplit_k(const float* __restrict__ W, unsigned short* __restrict__ Th,
              unsigned short* __restrict__ Tl)
{
    __shared__ float Ls[64][68];   // 272B stride: float4 ops stay 16B-aligned
    const int n0 = blockIdx.x << 6, k0 = blockIdx.y << 6;
    const int tid = threadIdx.x;
    const int r16 = tid >> 4, c4 = (tid & 15) << 2;
#pragma unroll
    for (int j = 0; j < 4; ++j) {
        const int row = r16 + (j << 4);
        *(float4*)&Ls[row][c4] = *(const float4*)&W[(size_t)(k0 + row) * ND + n0 + c4];
    }
    __syncthreads();
#pragma unroll
    for (int j = 0; j < 4; ++j) {
        const int n = r16 + (j << 4);
        ushort4 hh, ll;
        split_bf16(Ls[c4 + 0][n], hh.x, ll.x);
        split_bf16(Ls[c4 + 1][n], hh.y, ll.y);
        split_bf16(Ls[c4 + 2][n], hh.z, ll.z);
        split_bf16(Ls[c4 + 3][n], hh.w, ll.w);
        const size_t o = (size_t)(n0 + n) * ND + k0 + c4;
        *(ushort4*)&Th[o] = hh;
        *(ushort4*)&Tl[o] = ll;
    }
}

// Wg [k][n] fp32 -> WT [n][k] RNE h/m/l planes.
__global__ __launch_bounds__(256)
void tsplit3_k(const float* __restrict__ W, unsigned short* __restrict__ T0,
               unsigned short* __restrict__ T1, unsigned short* __restrict__ T2)
{
    __shared__ float Ls[64][68];
    const int n0 = blockIdx.x << 6, k0 = blockIdx.y << 6;
    const int tid = threadIdx.x;
    const int r16 = tid >> 4, c4 = (tid & 15) << 2;
#pragma unroll
    for (int j = 0; j < 4; ++j) {
        const int row = r16 + (j << 4);
        *(float4*)&Ls[row][c4] = *(const float4*)&W[(size_t)(k0 + row) * ND + n0 + c4];
    }
    __syncthreads();
#pragma unroll
    for (int j = 0; j < 4; ++j) {
        const int n = r16 + (j << 4);
        ushort4 hh, mm, ll;
        split3(Ls[c4 + 0][n], hh.x, mm.x, ll.x);
        split3(Ls[c4 + 1][n], hh.y, mm.y, ll.y);
        split3(Ls[c4 + 2][n], hh.z, mm.z, ll.z);
        split3(Ls[c4 + 3][n], hh.w, mm.w, ll.w);
        const size_t o = (size_t)(n0 + n) * ND + k0 + c4;
        *(ushort4*)&T0[o] = hh;
        *(ushort4*)&T1[o] = mm;
        *(ushort4*)&T2[o] = ll;
    }
}

// ---------------------------------------------------------------- windowed-sum machinery
__global__ __launch_bounds__(64)
void chunkscan_k(const float* __restrict__ g, float* __restrict__ Pin,
                 float* __restrict__ Csum)
{
    const int blk = blockIdx.x;
    const int lane = threadIdx.x;
    const int base = (blk << 12) + lane;
    float run = 0.f;
#pragma unroll 16
    for (int t = 0; t < 64; ++t) {
        run += g[base + (t << 6)];
        Pin[base + (t << 6)] = run;
    }
    Csum[(blk << 6) + lane] = run;
}

__global__ __launch_bounds__(64)
void chunkpre_k(const float* __restrict__ Csum, float* __restrict__ Cpre)
{
    const int bh = blockIdx.x, lane = threadIdx.x;
    float run = 0.f;
    for (int c = 0; c < NCH; ++c) {
        run += Csum[((bh * NCH + c) << 6) + lane];
        Cpre[((bh * NCH + c) << 6) + lane] = run;
    }
}

__global__ __launch_bounds__(256)
void winsum_k(const float* __restrict__ Pin, const float* __restrict__ Cpre,
              float* __restrict__ wout)
{
    const int idx = blockIdx.x * 256 + threadIdx.x;
    const int e0 = idx << 2;
    const int row = e0 >> 6;
    const int d = e0 & 63;
    const int bh = row >> 11;
    const int i = row & (NT - 1);
    const int c = i >> 6;

    float4 p = *(const float4*)&Pin[e0];
    float ax = p.x, ay = p.y, az = p.z, aw = p.w;
    if (c > 0) {
        const float4 q = *(const float4*)&Cpre[((bh * NCH + c - 1) << 6) + d];
        ax += q.x; ay += q.y; az += q.z; aw += q.w;
    }
    if (i >= WIN) {
        const int i2 = i - WIN;
        const int c2 = i2 >> 6;
        const float4 p2 = *(const float4*)&Pin[(((bh << 11) + i2) << 6) + d];
        ax -= p2.x; ay -= p2.y; az -= p2.z; aw -= p2.w;
        if (c2 > 0) {
            const float4 q2 = *(const float4*)&Cpre[((bh * NCH + c2 - 1) << 6) + d];
            ax -= q2.x; ay -= q2.y; az -= q2.z; aw -= q2.w;
        }
    }
    *(float4*)&wout[e0] = make_float4(ax, ay, az, aw);
}

__global__ __launch_bounds__(256)
void stats_k(float* __restrict__ wing, double* __restrict__ rowsum)
{
    const int row = (blockIdx.x << 2) + (threadIdx.x >> 6);
    const int lane = threadIdx.x & 63;
    const int i = row & (NT - 1);
    const float w = wing[(row << 6) + lane];
    const double cnt = (double)((i + 1 < WIN) ? (i + 1) : WIN);
    const double denom = (double)w / cnt + 0.5;
    double s = 1.0 / denom;
#pragma unroll
    for (int off = 32; off > 0; off >>= 1) s += __shfl_xor(s, off);
    const double gf = 1.0 / (denom * s);
    double rw = gf * (double)w;
#pragma unroll
    for (int off = 32; off > 0; off >>= 1) rw += __shfl_xor(rw, off);
    wing[(row << 6) + lane] = (float)gf;
    if (lane == 0) rowsum[row] = rw;
}

// ---------------------------------------------------------------- banded attention (MFMA)
__global__ __launch_bounds__(256)
void attn_k(const float* __restrict__ gf, const float* __restrict__ g,
            const float* __restrict__ v, const double* __restrict__ rowsum,
            unsigned short* __restrict__ aoh, unsigned short* __restrict__ aol)
{
    __shared__ unsigned short gL[64 * 72];   // [j][d] bf16
    __shared__ unsigned short VT[64 * 72];   // [d][j] bf16
    __shared__ unsigned short SL[64 * 72];   // [i][j] bf16, wave-private 16-row bands

    const int bh = blockIdx.y, it = blockIdx.x;
    const int i0 = it << 6;
    const int tid = threadIdx.x;
    const int wave = tid >> 6, lane = tid & 63;
    const int l15 = lane & 15, l4 = lane >> 4;

    bf16x8 gfB[2];
    {
        const int ig = i0 + (wave << 4) + l15;
        const float* src = gf + (((size_t)(bh << 11) + ig) << 6) + (l4 << 3);
        const float4 q0 = *(const float4*)(src);
        const float4 q1 = *(const float4*)(src + 4);
        const float4 q2 = *(const float4*)(src + 32);
        const float4 q3 = *(const float4*)(src + 36);
        const us8 f0 = pack8(q0, q1), f1 = pack8(q2, q3);
        gfB[0] = (bf16x8)f0;
        gfB[1] = (bf16x8)f1;
    }

    const int sj = lane, sd0 = wave << 4;

    const int t_lo = (it >= 8) ? (it - 8) : 0;
    float4 gq[4], vq[4];
    {
        const float* gsrc = g + (((size_t)(bh << 11) + (t_lo << 6) + sj) << 6) + sd0;
        const float* vsrc = v + (((size_t)(bh << 11) + (t_lo << 6) + sj) << 6) + sd0;
#pragma unroll
        for (int q = 0; q < 4; ++q) gq[q] = *(const float4*)(gsrc + (q << 2));
#pragma unroll
        for (int q = 0; q < 4; ++q) vq[q] = *(const float4*)(vsrc + (q << 2));
    }

    f32x4 acc2[4] = {};
    const int ig_mask = i0 + (wave << 4) + l15;

    for (int t = t_lo; t <= it; ++t) {
        const int j0 = t << 6;
        __syncthreads();
        {
            *(us8*)&gL[sj * 72 + sd0]     = pack8(gq[0], gq[1]);
            *(us8*)&gL[sj * 72 + sd0 + 8] = pack8(gq[2], gq[3]);
            const float* vf = (const float*)vq;
#pragma unroll
            for (int h = 0; h < 16; ++h)
                VT[(sd0 + h) * 72 + sj] = bf_rne(vf[h]);
        }
        __syncthreads();

        if (t < it) {
            const float* gsrc = g + (((size_t)(bh << 11) + j0 + 64 + sj) << 6) + sd0;
            const float* vsrc = v + (((size_t)(bh << 11) + j0 + 64 + sj) << 6) + sd0;
#pragma unroll
            for (int q = 0; q < 4; ++q) gq[q] = *(const float4*)(gsrc + (q << 2));
#pragma unroll
            for (int q = 0; q < 4; ++q) vq[q] = *(const float4*)(vsrc + (q << 2));
        }

        f32x4 sfr[4] = {};
#pragma unroll
        for (int kk = 0; kk < 2; ++kk)
#pragma unroll
            for (int jm = 0; jm < 4; ++jm) {
                const bf16x8 ag = *(const bf16x8*)&gL[((jm << 4) + l15) * 72 + (kk << 5) + (l4 << 3)];
                sfr[jm] = __builtin_amdgcn_mfma_f32_16x16x32_bf16(ag, gfB[kk], sfr[jm], 0, 0, 0);
            }

        const bool need_mask = (t == it) || (t == it - 8);
#pragma unroll
        for (int jm = 0; jm < 4; ++jm) {
            float s0 = sfr[jm][0], s1 = sfr[jm][1], s2 = sfr[jm][2], s3 = sfr[jm][3];
            if (need_mask) {
                const int jb = j0 + (jm << 4) + (l4 << 2);
                if (!(jb + 0 <= ig_mask && jb + 0 > ig_mask - WIN)) s0 = 0.f;
                if (!(jb + 1 <= ig_mask && jb + 1 > ig_mask - WIN)) s1 = 0.f;
                if (!(jb + 2 <= ig_mask && jb + 2 > ig_mask - WIN)) s2 = 0.f;
                if (!(jb + 3 <= ig_mask && jb + 3 > ig_mask - WIN)) s3 = 0.f;
            }
            us4 sl;
            sl[0] = bf_rne(s0); sl[1] = bf_rne(s1); sl[2] = bf_rne(s2); sl[3] = bf_rne(s3);
            *(us4*)&SL[((wave << 4) + l15) * 72 + (jm << 4) + (l4 << 2)] = sl;
        }

#pragma unroll
        for (int kk = 0; kk < 2; ++kk) {
            const bf16x8 a2 = *(const bf16x8*)&SL[((wave << 4) + l15) * 72 + (kk << 5) + (l4 << 3)];
#pragma unroll
            for (int nf = 0; nf < 4; ++nf) {
                const bf16x8 b2 = *(const bf16x8*)&VT[((nf << 4) + l15) * 72 + (kk << 5) + (l4 << 3)];
                acc2[nf] = __builtin_amdgcn_mfma_f32_16x16x32_bf16(a2, b2, acc2[nf], 0, 0, 0);
            }
        }
    }

    const int b = bh >> 4, hh = bh & 15;
    float inv[4];
#pragma unroll
    for (int r = 0; r < 4; ++r) {
        const int ig = i0 + (wave << 4) + (l4 << 2) + r;
        double rs = rowsum[(bh << 11) + ig];
        if (!(rs > 1e-10)) rs = 1e-10;
        inv[r] = (float)(1.0 / rs);
    }
#pragma unroll
    for (int nf = 0; nf < 4; ++nf)
#pragma unroll
        for (int r = 0; r < 4; ++r) {
            const int ig = i0 + (wave << 4) + (l4 << 2) + r;
            const int d = (nf << 4) + l15;
            const float val = acc2[nf][r] * inv[r];
            unsigned short vh, vl;
            split_bf16(val, vh, vl);
            const size_t base = (((size_t)(b * NT + ig)) << 10) + (hh << 6) + d;
            aoh[base] = vh;
            aol[base] = vl;
        }
}

// ---------------------------------------------------------------- launch
// Workspace map (~78 MB; overlays have disjoint live ranges):
//   gbuf [SZ]    g          (mgemm3 -> attn)
//   vbuf [SZ]    v          (mgemm<1> -> attn)
//   pinb [SZ]    xl (split3 -> mgemm3), then prefixes (chunkscan -> winsum),
//                then aoh/aol (attn -> mgemm<0>)
//   winb [SZ]    xh+xm (split3 -> mgemm<1>), then gene_fit (winsum -> attn)
//   wpl  [7*MW us] wvT h/l, woT h/l, wgT 0/1/2 (tsplit -> mgemms)
//   csum/cpre/rsum overlay wgT planes (dead after mgemm3; born at chunkscan)
extern "C" void kernel_launch(void* const* d_in, const int* in_sizes, int n_in,
                              void* d_out, int out_size, void* d_ws, size_t ws_size,
                              hipStream_t stream)
{
    const float* x  = (const float*)d_in[0];
    const float* Wg = (const float*)d_in[1];
    const float* bg = (const float*)d_in[2];
    const float* Wv = (const float*)d_in[3];
    const float* bv = (const float*)d_in[4];
    const float* Wo = (const float*)d_in[5];
    const float* bo = (const float*)d_in[6];
    float* out = (float*)d_out;

    const size_t SZ = (size_t)NB * NH * NT * HD;   // 4M floats
    const size_t MW = (size_t)ND * ND;             // 1M
    const size_t CS = (size_t)NBH * NCH * HD;      // 64K

    float* gbuf = (float*)d_ws;
    float* vbuf = gbuf + SZ;
    float* pinb = vbuf + SZ;
    float* winb = pinb + SZ;
    float* wpl  = winb + SZ;

    unsigned short* wvTh = (unsigned short*)wpl;
    unsigned short* wvTl = wvTh + MW;
    unsigned short* woTh = wvTl + MW;
    unsigned short* woTl = woTh + MW;
    unsigned short* wgT0 = woTl + MW;
    unsigned short* wgT1 = wgT0 + MW;
    unsigned short* wgT2 = wgT1 + MW;

    float* csum = (float*)wgT0;            // overlay: wgT dead after mgemm3
    float* cpre = csum + CS;
    double* rsum = (double*)(cpre + CS);

    unsigned short* xh  = (unsigned short*)winb;
    unsigned short* xm  = xh + SZ;
    unsigned short* xl  = (unsigned short*)pinb;   // dead before chunkscan writes pinb
    unsigned short* aoh = (unsigned short*)pinb;
    unsigned short* aol = aoh + SZ;

    const int M = NB * NT;   // 4096

    split3_k<<<(int)(SZ / 4 / 256), 256, 0, stream>>>(x, xh, xm, xl);
    tsplit3_k<<<dim3(ND >> 6, ND >> 6), 256, 0, stream>>>(Wg, wgT0, wgT1, wgT2);
    tsplit_k<<<dim3(ND >> 6, ND >> 6), 256, 0, stream>>>(Wv, wvTh, wvTl);
    tsplit_k<<<dim3(ND >> 6, ND >> 6), 256, 0, stream>>>(Wo, woTh, woTl);
    mgemm3_k<<<dim3(ND >> 7, M >> 7), 256, 0, stream>>>(xh, xm, xl, wgT0, wgT1, wgT2, bg, gbuf, M, ND, ND);
    mgemm_k<1><<<dim3(ND >> 7, M >> 7), 256, 0, stream>>>(xh, xm, wvTh, wvTl, bv, vbuf, M, ND, ND);
    chunkscan_k<<<NBH * NCH, 64, 0, stream>>>(gbuf, pinb, csum);
    chunkpre_k<<<NBH, 64, 0, stream>>>(csum, cpre);
    winsum_k<<<(NBH * NT * HD / 4) / 256, 256, 0, stream>>>(pinb, cpre, winb);
    stats_k<<<(NBH * NT) / 4, 256, 0, stream>>>(winb, rsum);
    attn_k<<<dim3(NT >> 6, NBH), 256, 0, stream>>>(winb, gbuf, vbuf, rsum, aoh, aol);
    mgemm_k<0><<<dim3(ND >> 7, M >> 7), 256, 0, stream>>>(aoh, aol, woTh, woTl, bo, out, M, ND, ND);
}